// Round 4
// baseline (379.787 us; speedup 1.0000x reference)
//
#include <hip/hip_runtime.h>
#include <stdint.h>
#include <math.h>

typedef unsigned short u16;
typedef uint32_t u32;
typedef short bf16x8 __attribute__((ext_vector_type(8)));   // 8 bf16 = 4 VGPRs
typedef float f32x4  __attribute__((ext_vector_type(4)));

#define DEV __device__ __forceinline__

DEV u16 f2bf(float f) {
    union { float f; u32 u; } x; x.f = f;
    u32 lsb = (x.u >> 16) & 1u;
    x.u += 0x7fffu + lsb;            // RNE
    return (u16)(x.u >> 16);
}

// pack two f32 -> two bf16 (round-half-up) in 3 VALU ops
DEV u32 pack2(float a, float b) {
    union { float f; u32 u; } x, y; x.f = a; y.f = b;
    return __builtin_amdgcn_perm(y.u + 0x8000u, x.u + 0x8000u, 0x07060302u);
}

#if __has_builtin(__builtin_amdgcn_exp2f)
DEV float fexp2(float x) { return __builtin_amdgcn_exp2f(x); }
#else
DEV float fexp2(float x) { return __expf(x * 0.69314718056f); }
#endif

DEV f32x4 mfma16(bf16x8 a, bf16x8 b, f32x4 c) {
    return __builtin_amdgcn_mfma_f32_16x16x32_bf16(a, b, c, 0, 0, 0);
}

// ---------------------------------------------------------------------------
// 0) Convert the four f32 weight matrices to bf16: dst[j][co][ci], j=q,k,v,p
// ---------------------------------------------------------------------------
__global__ __launch_bounds__(256) void convert_w_kernel(const float* __restrict__ w0,
                                                        const float* __restrict__ w1,
                                                        const float* __restrict__ w2,
                                                        const float* __restrict__ w3,
                                                        u16* __restrict__ dst) {
    const float* src = (blockIdx.y == 0) ? w0 : (blockIdx.y == 1) ? w1
                     : (blockIdx.y == 2) ? w2 : w3;
    int idx = (blockIdx.x * 256 + threadIdx.x) * 4;   // over 512*512 = 262144
    float4 v = *(const float4*)&src[idx];
    uint2 pv;
    pv.x = pack2(v.x, v.y);
    pv.y = pack2(v.z, v.w);
    *(uint2*)&dst[(size_t)blockIdx.y * 262144 + idx] = pv;
}

// ---------------------------------------------------------------------------
// 1) Transpose+convert x[b][c][s] (f32) -> tok[b][s][c] (bf16)   C=512, S=4096
// ---------------------------------------------------------------------------
__global__ __launch_bounds__(256) void transpose_kernel(const float* __restrict__ x,
                                                        u16* __restrict__ tok) {
    __shared__ u16 t[64][65];
    const int b = blockIdx.z, c0 = blockIdx.y * 64, s0 = blockIdx.x * 64;
    const float* xb = x + ((size_t)b * 512 + c0) * 4096 + s0;
    u16* tb = tok + ((size_t)b * 4096 + s0) * 512 + c0;
    const int tid = threadIdx.x;
    {   // read: 64 rows (c) x 16 float4 cols (s)
        const int jc = tid & 15, i0 = tid >> 4;
#pragma unroll
        for (int ii = 0; ii < 4; ii++) {
            int i = i0 * 4 + ii;
            float4 v = *(const float4*)&xb[(size_t)i * 4096 + jc * 4];
            t[i][jc * 4 + 0] = f2bf(v.x);
            t[i][jc * 4 + 1] = f2bf(v.y);
            t[i][jc * 4 + 2] = f2bf(v.z);
            t[i][jc * 4 + 3] = f2bf(v.w);
        }
    }
    __syncthreads();
    {   // write: 64 rows (s) x 32 u32 cols (c pairs)
        const int j = tid & 31, i0 = tid >> 5;
#pragma unroll
        for (int ii = 0; ii < 8; ii++) {
            int srow = i0 * 8 + ii;
            u32 v = (u32)t[j * 2][srow] | ((u32)t[j * 2 + 1][srow] << 16);
            *(u32*)(&tb[(size_t)srow * 512 + j * 2]) = v;
        }
    }
}

// ---------------------------------------------------------------------------
// 2) Projection GEMM core: out[co][s] = (sum_c W[co][c]*Bb[s][c] + bias[co])*scale
//    M-tile 64 (co), N-tile 128 (s), BK=64, 4 waves (wave owns 32 n-cols).
//    LDS frag order: granule(rt,ks,q,r) -> 16B of row rt*16+r, k ks*32+q*8.
//    mode 0: out bf16 [b][hd][s][d]   mode 1: out bf16 [b*512+co][s]
//    mode 2: out f32  [b*512+co][s]
// ---------------------------------------------------------------------------
DEV void proj_core(const u16* __restrict__ W, const float* __restrict__ bias,
                   const u16* __restrict__ Bb, void* __restrict__ out,
                   int b, int mode, float scale,
                   u16* __restrict__ Alds, u16* __restrict__ Blds) {
    const int tid = threadIdx.x;
    const int wave = tid >> 6, lane = tid & 63, q = lane >> 4, c = lane & 15;
    const int m0 = blockIdx.y * 64, n0 = blockIdx.x * 128;

    f32x4 acc[4][2] = {};

    for (int k0 = 0; k0 < 512; k0 += 64) {
        __syncthreads();
#pragma unroll
        for (int i = 0; i < 2; i++) {   // A: 512 granules (64x64), 2/thread
            int g = tid + i * 256;
            int r = g & 15, qq = (g >> 4) & 3, ks = (g >> 6) & 1, rt = g >> 7;
            int col = k0 + ks * 32 + qq * 8;
            *(int4*)&Alds[g * 8] = *(const int4*)&W[(size_t)(m0 + rt * 16 + r) * 512 + col];
        }
#pragma unroll
        for (int i = 0; i < 4; i++) {   // B: 1024 granules (128x64), 4/thread
            int g = tid + i * 256;
            int r = g & 15, qq = (g >> 4) & 3, ks = (g >> 6) & 1, rt = g >> 7;
            int col = k0 + ks * 32 + qq * 8;
            *(int4*)&Blds[g * 8] = *(const int4*)&Bb[(size_t)(n0 + rt * 16 + r) * 512 + col];
        }
        __syncthreads();
#pragma unroll
        for (int ks = 0; ks < 2; ks++) {
            bf16x8 af[4], bfr[2];
#pragma unroll
            for (int mt = 0; mt < 4; mt++)
                af[mt] = *(const bf16x8*)&Alds[(((mt * 2 + ks) * 4 + q) * 16 + c) * 8];
#pragma unroll
            for (int nt = 0; nt < 2; nt++) {
                int ntg = wave * 2 + nt;
                bfr[nt] = *(const bf16x8*)&Blds[(((ntg * 2 + ks) * 4 + q) * 16 + c) * 8];
            }
#pragma unroll
            for (int mt = 0; mt < 4; mt++)
#pragma unroll
                for (int nt = 0; nt < 2; nt++)
                    acc[mt][nt] = mfma16(af[mt], bfr[nt], acc[mt][nt]);
        }
    }

    // epilogue: co = m0+mt*16+q*4+reg ; s = n0+wave*32+nt*16+c
#pragma unroll
    for (int mt = 0; mt < 4; mt++) {
        int co0 = m0 + mt * 16 + q * 4;
        float b0 = bias[co0 + 0], b1 = bias[co0 + 1];
        float b2 = bias[co0 + 2], b3 = bias[co0 + 3];
#pragma unroll
        for (int nt = 0; nt < 2; nt++) {
            int scol = n0 + wave * 32 + nt * 16 + c;
            float v0 = (acc[mt][nt][0] + b0) * scale;
            float v1 = (acc[mt][nt][1] + b1) * scale;
            float v2 = (acc[mt][nt][2] + b2) * scale;
            float v3 = (acc[mt][nt][3] + b3) * scale;
            if (mode == 0) {
                uint2 pv; pv.x = pack2(v0, v1); pv.y = pack2(v2, v3);
                size_t idx = ((size_t)(b * 8 + (co0 >> 6)) * 4096 + scol) * 64 + (co0 & 63);
                *(uint2*)&((u16*)out)[idx] = pv;
            } else if (mode == 1) {
                u16* o = (u16*)out;
                o[((size_t)(b * 512 + co0 + 0)) * 4096 + scol] = f2bf(v0);
                o[((size_t)(b * 512 + co0 + 1)) * 4096 + scol] = f2bf(v1);
                o[((size_t)(b * 512 + co0 + 2)) * 4096 + scol] = f2bf(v2);
                o[((size_t)(b * 512 + co0 + 3)) * 4096 + scol] = f2bf(v3);
            } else {
                float* o = (float*)out;
                o[((size_t)(b * 512 + co0 + 0)) * 4096 + scol] = v0;
                o[((size_t)(b * 512 + co0 + 1)) * 4096 + scol] = v1;
                o[((size_t)(b * 512 + co0 + 2)) * 4096 + scol] = v2;
                o[((size_t)(b * 512 + co0 + 3)) * 4096 + scol] = v3;
            }
        }
    }
}

// fused Q/K/V projection: blockIdx.z in [0,6): j = z>>1 (0=Q,1=K,2=V), b = z&1
// Q is pre-scaled by log2(e)/8 so attention scores are in the exp2 domain.
__global__ __launch_bounds__(256) void qkv_kernel(const u16* __restrict__ Wbf,
                                                  const float* __restrict__ bq,
                                                  const float* __restrict__ bk,
                                                  const float* __restrict__ bv,
                                                  const u16* __restrict__ tok,
                                                  u16* __restrict__ Qb,
                                                  u16* __restrict__ Kb,
                                                  u16* __restrict__ Vb) {
    __shared__ u16 Alds[4096];    // 8KB
    __shared__ u16 Blds[8192];    // 16KB
    const int z = blockIdx.z, j = z >> 1, b = z & 1;
    const u16* W = Wbf + (size_t)j * 262144;
    const float* bias = (j == 0) ? bq : (j == 1) ? bk : bv;
    void* out = (j == 0) ? (void*)Qb : (j == 1) ? (void*)Kb : (void*)Vb;
    const float scale = (j == 0) ? 0.1803368801f : 1.0f;   // log2(e)/8
    const int mode = (j == 2) ? 1 : 0;
    proj_core(W, bias, tok + (size_t)b * (4096 * 512), out, b, mode, scale, Alds, Blds);
}

// final projection: blockIdx.z = batch, f32 output
__global__ __launch_bounds__(256) void projp_kernel(const u16* __restrict__ Wp,
                                                    const float* __restrict__ bp,
                                                    const u16* __restrict__ attout,
                                                    float* __restrict__ out) {
    __shared__ u16 Alds[4096];
    __shared__ u16 Blds[8192];
    const int b = blockIdx.z;
    proj_core(Wp, bp, attout + (size_t)b * (4096 * 512), out, b, 2, 1.0f, Alds, Blds);
}

// ---------------------------------------------------------------------------
// 3) Flash attention, fixed-base softmax (scores already in exp2 domain; f32
//    exp2 cannot overflow at these magnitudes, softmax is shift-invariant).
//    Q[bhd][s][64], K[bhd][t][64], VT[bhd][64][t]. BM=128 (4 waves x 32 s),
//    BN=64 t-tiles. grid.z splits the t-range for 2x occupancy; halves are
//    combined via f32 atomicAdd into Oacc/lacc (exactly 2 writers/address),
//    then attn_norm_kernel normalizes. combine=0: single-range fallback that
//    normalizes in-kernel and writes attout directly.
// ---------------------------------------------------------------------------
__global__ __launch_bounds__(256) void attn_kernel(const u16* __restrict__ Qm,
                                                   const u16* __restrict__ Km,
                                                   const u16* __restrict__ Vm,
                                                   float* __restrict__ Oacc,
                                                   float* __restrict__ lacc,
                                                   u16* __restrict__ attout,
                                                   int t_count, int combine) {
    __shared__ u16 Klds[4096];        // 8KB, frag order (tt,kd,q,r)
    __shared__ u16 Vlds[4096];        // 8KB, frag order (dt,kt,q,r)
    __shared__ u16 Plds[128 * 72];    // [s_local][72] padded, 18KB (16B-aligned rows)
    const int tid = threadIdx.x, wave = tid >> 6, lane = tid & 63;
    const int q = lane >> 4, c = lane & 15;
    const int bhd = blockIdx.y, s0 = blockIdx.x * 128;
    const int t_base = blockIdx.z * t_count;
    const u16* Qb = Qm + (size_t)bhd * (4096 * 64);
    const u16* Kb = Km + (size_t)bhd * (4096 * 64);
    const u16* Vb = Vm + (size_t)bhd * (64 * 4096);

    // Q B-frags, held in registers the whole kernel (Q pre-scaled by log2e/8)
    bf16x8 qf[2][2];
#pragma unroll
    for (int st = 0; st < 2; st++)
#pragma unroll
        for (int kd = 0; kd < 2; kd++)
            qf[st][kd] = *(const bf16x8*)
                &Qb[(size_t)(s0 + wave * 32 + st * 16 + c) * 64 + kd * 32 + q * 8];

    f32x4 oacc[4][2] = {};            // [dt][st]: O^T rows dv, cols s
    float lsum[2] = {0.f, 0.f};

    for (int t0 = t_base; t0 < t_base + t_count; t0 += 64) {
        __syncthreads();
        // stage K and V^T in A-frag order
#pragma unroll
        for (int i = 0; i < 2; i++) {
            int g = tid + i * 256;    // 512 granules of 16B each
            int r = g & 15, qq = (g >> 4) & 3, kk = (g >> 6) & 1, t4 = g >> 7;
            *(int4*)&Klds[g * 8] =
                *(const int4*)&Kb[(size_t)(t0 + t4 * 16 + r) * 64 + kk * 32 + qq * 8];
            *(int4*)&Vlds[g * 8] =
                *(const int4*)&Vb[(size_t)(t4 * 16 + r) * 4096 + t0 + kk * 32 + qq * 8];
        }
        __syncthreads();

        // S^T tile: rows t (4 tiles), cols s (wave's 2 tiles)
        f32x4 sacc[4][2] = {};
#pragma unroll
        for (int kd = 0; kd < 2; kd++) {
            bf16x8 ka[4];
#pragma unroll
            for (int tt = 0; tt < 4; tt++)
                ka[tt] = *(const bf16x8*)&Klds[(((tt * 2 + kd) * 4 + q) * 16 + c) * 8];
#pragma unroll
            for (int tt = 0; tt < 4; tt++)
#pragma unroll
                for (int st = 0; st < 2; st++)
                    sacc[tt][st] = mfma16(ka[tt], qf[st][kd], sacc[tt][st]);
        }

        // p = exp2(score); accumulate denominator per-lane; pack P^T -> LDS
#pragma unroll
        for (int st = 0; st < 2; st++) {
#pragma unroll
            for (int tt = 0; tt < 4; tt++) {
                float p0 = fexp2(sacc[tt][st][0]);
                float p1 = fexp2(sacc[tt][st][1]);
                float p2 = fexp2(sacc[tt][st][2]);
                float p3 = fexp2(sacc[tt][st][3]);
                lsum[st] += (p0 + p1) + (p2 + p3);
                uint2 pv; pv.x = pack2(p0, p1); pv.y = pack2(p2, p3);
                *(uint2*)&Plds[(size_t)(wave * 32 + st * 16 + c) * 72 + tt * 16 + q * 4] = pv;
            }
        }
        __syncthreads();   // P visible across quads (cross-lane LDS dependency)

        // O^T += VT x P^T  (A = VT rows dv, B = Plds rows s; k = t)
#pragma unroll
        for (int kt = 0; kt < 2; kt++) {
            bf16x8 va[4], pb[2];
#pragma unroll
            for (int dt = 0; dt < 4; dt++)
                va[dt] = *(const bf16x8*)&Vlds[(((dt * 2 + kt) * 4 + q) * 16 + c) * 8];
#pragma unroll
            for (int st = 0; st < 2; st++)
                pb[st] = *(const bf16x8*)
                    &Plds[(size_t)(wave * 32 + st * 16 + c) * 72 + kt * 32 + q * 8];
#pragma unroll
            for (int dt = 0; dt < 4; dt++)
#pragma unroll
                for (int st = 0; st < 2; st++)
                    oacc[dt][st] = mfma16(va[dt], pb[st], oacc[dt][st]);
        }
    }

    if (combine) {
        // partial epilogue: unnormalized accumulate (2 writers per address)
#pragma unroll
        for (int st = 0; st < 2; st++) {
            int s = s0 + wave * 32 + st * 16 + c;
            atomicAdd(&lacc[bhd * 4096 + s], lsum[st]);   // 4 quads x 2 halves
#pragma unroll
            for (int dt = 0; dt < 4; dt++) {
                size_t base = ((size_t)bhd * 4096 + s) * 64 + dt * 16 + q * 4;
                atomicAdd(&Oacc[base + 0], oacc[dt][st][0]);
                atomicAdd(&Oacc[base + 1], oacc[dt][st][1]);
                atomicAdd(&Oacc[base + 2], oacc[dt][st][2]);
                atomicAdd(&Oacc[base + 3], oacc[dt][st][3]);
            }
        }
    } else {
        // single-pass epilogue: attout[b][s][hd*64+dv]
        const int b = bhd >> 3, hd = bhd & 7;
#pragma unroll
        for (int st = 0; st < 2; st++) {
            float l = lsum[st];
            l += __shfl_xor(l, 16, 64);
            l += __shfl_xor(l, 32, 64);
            float rl = 1.0f / l;
            int s = s0 + wave * 32 + st * 16 + c;
#pragma unroll
            for (int dt = 0; dt < 4; dt++) {
                uint2 pv;
                pv.x = pack2(oacc[dt][st][0] * rl, oacc[dt][st][1] * rl);
                pv.y = pack2(oacc[dt][st][2] * rl, oacc[dt][st][3] * rl);
                size_t idx = ((size_t)(b * 4096 + s)) * 512 + hd * 64 + dt * 16 + q * 4;
                *(uint2*)&attout[idx] = pv;
            }
        }
    }
}

// normalize + merge heads: attout[b][s][hd*64+dv] = Oacc[bhd][s][dv] / lacc[bhd][s]
__global__ __launch_bounds__(256) void attn_norm_kernel(const float* __restrict__ Oacc,
                                                        const float* __restrict__ lacc,
                                                        u16* __restrict__ attout) {
    const int bhd = blockIdx.y, tid = threadIdx.x;
    const int s = blockIdx.x * 16 + (tid >> 4), dv = (tid & 15) * 4;
    const int b = bhd >> 3, hd = bhd & 7;
    float4 o = *(const float4*)&Oacc[((size_t)bhd * 4096 + s) * 64 + dv];
    float rl = 1.0f / lacc[bhd * 4096 + s];
    uint2 pv;
    pv.x = pack2(o.x * rl, o.y * rl);
    pv.y = pack2(o.z * rl, o.w * rl);
    *(uint2*)&attout[((size_t)(b * 4096 + s)) * 512 + hd * 64 + dv] = pv;
}

// ---------------------------------------------------------------------------
extern "C" void kernel_launch(void* const* d_in, const int* in_sizes, int n_in,
                              void* d_out, int out_size, void* d_ws, size_t ws_size,
                              hipStream_t stream) {
    (void)in_sizes; (void)n_in; (void)out_size;
    const float* x  = (const float*)d_in[0];
    const float* Wq = (const float*)d_in[1];
    const float* bq = (const float*)d_in[2];
    const float* Wk = (const float*)d_in[3];
    const float* bk = (const float*)d_in[4];
    const float* Wv = (const float*)d_in[5];
    const float* bv = (const float*)d_in[6];
    const float* Wp = (const float*)d_in[7];
    const float* bp = (const float*)d_in[8];
    float* out = (float*)d_out;

    const size_t NTOK = (size_t)4 * 1024 * 1024;  // 2*4096*512 elements
    u16* tok = (u16*)d_ws;        // [2][4096][512] bf16; reused as attout later
    u16* Qb  = tok + NTOK;        // [16][4096][64]  (pre-scaled by log2e/8)
    u16* Kb  = Qb + NTOK;         // [16][4096][64]
    u16* Vb  = Kb + NTOK;         // [16][64][4096]
    u16* Wbf = Vb + NTOK;         // [4][512][512] bf16 (q,k,v,p)
    float* Oacc = (float*)(Wbf + 4 * 262144);     // [16][4096][64] f32
    float* lacc = Oacc + (size_t)16 * 4096 * 64;  // [16][4096] f32
    u16* attout = tok;            // alias: tok dead after V projection

    const size_t need = (size_t)((char*)(lacc + 16 * 4096) - (char*)d_ws);
    const int combine = (ws_size >= need) ? 1 : 0;

    if (combine)
        hipMemsetAsync(Oacc, 0, (size_t)(16 * 4096 * 64 + 16 * 4096) * sizeof(float), stream);
    convert_w_kernel<<<dim3(256, 4), 256, 0, stream>>>(Wq, Wk, Wv, Wp, Wbf);
    transpose_kernel<<<dim3(64, 8, 2), 256, 0, stream>>>(x, tok);
    qkv_kernel<<<dim3(32, 8, 6), 256, 0, stream>>>(Wbf, bq, bk, bv, tok, Qb, Kb, Vb);
    if (combine) {
        attn_kernel<<<dim3(32, 16, 2), 256, 0, stream>>>(Qb, Kb, Vb, Oacc, lacc, attout, 2048, 1);
        attn_norm_kernel<<<dim3(256, 16), 256, 0, stream>>>(Oacc, lacc, attout);
    } else {
        attn_kernel<<<dim3(32, 16, 1), 256, 0, stream>>>(Qb, Kb, Vb, Oacc, lacc, attout, 4096, 0);
    }
    projp_kernel<<<dim3(32, 8, 2), 256, 0, stream>>>(Wbf + 3 * 262144, bp, attout, out);
}

// Round 5
// 367.254 us; speedup vs baseline: 1.0341x; 1.0341x over previous
//
#include <hip/hip_runtime.h>
#include <stdint.h>
#include <math.h>

typedef unsigned short u16;
typedef uint32_t u32;
typedef short bf16x8 __attribute__((ext_vector_type(8)));   // 8 bf16 = 4 VGPRs
typedef float f32x4  __attribute__((ext_vector_type(4)));

#define DEV __device__ __forceinline__

DEV u16 f2bf(float f) {
    union { float f; u32 u; } x; x.f = f;
    u32 lsb = (x.u >> 16) & 1u;
    x.u += 0x7fffu + lsb;            // RNE
    return (u16)(x.u >> 16);
}

// pack two f32 -> two bf16 (round-half-up) in 3 VALU ops
DEV u32 pack2(float a, float b) {
    union { float f; u32 u; } x, y; x.f = a; y.f = b;
    return __builtin_amdgcn_perm(y.u + 0x8000u, x.u + 0x8000u, 0x07060302u);
}

#if __has_builtin(__builtin_amdgcn_exp2f)
DEV float fexp2(float x) { return __builtin_amdgcn_exp2f(x); }
#else
DEV float fexp2(float x) { return __expf(x * 0.69314718056f); }
#endif

DEV f32x4 mfma16(bf16x8 a, bf16x8 b, f32x4 c) {
    return __builtin_amdgcn_mfma_f32_16x16x32_bf16(a, b, c, 0, 0, 0);
}

// ---------------------------------------------------------------------------
// 0) Convert the four f32 weight matrices to bf16: dst[j][co][ci], j=q,k,v,p
// ---------------------------------------------------------------------------
__global__ __launch_bounds__(256) void convert_w_kernel(const float* __restrict__ w0,
                                                        const float* __restrict__ w1,
                                                        const float* __restrict__ w2,
                                                        const float* __restrict__ w3,
                                                        u16* __restrict__ dst) {
    const float* src = (blockIdx.y == 0) ? w0 : (blockIdx.y == 1) ? w1
                     : (blockIdx.y == 2) ? w2 : w3;
    int idx = (blockIdx.x * 256 + threadIdx.x) * 4;   // over 512*512 = 262144
    float4 v = *(const float4*)&src[idx];
    uint2 pv;
    pv.x = pack2(v.x, v.y);
    pv.y = pack2(v.z, v.w);
    *(uint2*)&dst[(size_t)blockIdx.y * 262144 + idx] = pv;
}

// ---------------------------------------------------------------------------
// 1) Transpose+convert x[b][c][s] (f32) -> tok[b][s][c] (bf16)   C=512, S=4096
// ---------------------------------------------------------------------------
__global__ __launch_bounds__(256) void transpose_kernel(const float* __restrict__ x,
                                                        u16* __restrict__ tok) {
    __shared__ u16 t[64][65];
    const int b = blockIdx.z, c0 = blockIdx.y * 64, s0 = blockIdx.x * 64;
    const float* xb = x + ((size_t)b * 512 + c0) * 4096 + s0;
    u16* tb = tok + ((size_t)b * 4096 + s0) * 512 + c0;
    const int tid = threadIdx.x;
    {   // read: 64 rows (c) x 16 float4 cols (s)
        const int jc = tid & 15, i0 = tid >> 4;
#pragma unroll
        for (int ii = 0; ii < 4; ii++) {
            int i = i0 * 4 + ii;
            float4 v = *(const float4*)&xb[(size_t)i * 4096 + jc * 4];
            t[i][jc * 4 + 0] = f2bf(v.x);
            t[i][jc * 4 + 1] = f2bf(v.y);
            t[i][jc * 4 + 2] = f2bf(v.z);
            t[i][jc * 4 + 3] = f2bf(v.w);
        }
    }
    __syncthreads();
    {   // write: 64 rows (s) x 32 u32 cols (c pairs)
        const int j = tid & 31, i0 = tid >> 5;
#pragma unroll
        for (int ii = 0; ii < 8; ii++) {
            int srow = i0 * 8 + ii;
            u32 v = (u32)t[j * 2][srow] | ((u32)t[j * 2 + 1][srow] << 16);
            *(u32*)(&tb[(size_t)srow * 512 + j * 2]) = v;
        }
    }
}

// ---------------------------------------------------------------------------
// 2) Projection GEMM core: out[co][s] = (sum_c W[co][c]*Bb[s][c] + bias[co])*scale
//    M-tile 64 (co), N-tile 128 (s), BK=64, 4 waves (wave owns 32 n-cols).
//    LDS frag order: granule(rt,ks,q,r) -> 16B of row rt*16+r, k ks*32+q*8.
//    mode 0: out bf16 [b][hd][s][d]   mode 1: out bf16 [b*512+co][s]
//    mode 2: out f32  [b*512+co][s]
// ---------------------------------------------------------------------------
DEV void proj_core(const u16* __restrict__ W, const float* __restrict__ bias,
                   const u16* __restrict__ Bb, void* __restrict__ out,
                   int b, int mode, float scale,
                   u16* __restrict__ Alds, u16* __restrict__ Blds) {
    const int tid = threadIdx.x;
    const int wave = tid >> 6, lane = tid & 63, q = lane >> 4, c = lane & 15;
    const int m0 = blockIdx.y * 64, n0 = blockIdx.x * 128;

    f32x4 acc[4][2] = {};

    for (int k0 = 0; k0 < 512; k0 += 64) {
        __syncthreads();
#pragma unroll
        for (int i = 0; i < 2; i++) {   // A: 512 granules (64x64), 2/thread
            int g = tid + i * 256;
            int r = g & 15, qq = (g >> 4) & 3, ks = (g >> 6) & 1, rt = g >> 7;
            int col = k0 + ks * 32 + qq * 8;
            *(int4*)&Alds[g * 8] = *(const int4*)&W[(size_t)(m0 + rt * 16 + r) * 512 + col];
        }
#pragma unroll
        for (int i = 0; i < 4; i++) {   // B: 1024 granules (128x64), 4/thread
            int g = tid + i * 256;
            int r = g & 15, qq = (g >> 4) & 3, ks = (g >> 6) & 1, rt = g >> 7;
            int col = k0 + ks * 32 + qq * 8;
            *(int4*)&Blds[g * 8] = *(const int4*)&Bb[(size_t)(n0 + rt * 16 + r) * 512 + col];
        }
        __syncthreads();
#pragma unroll
        for (int ks = 0; ks < 2; ks++) {
            bf16x8 af[4], bfr[2];
#pragma unroll
            for (int mt = 0; mt < 4; mt++)
                af[mt] = *(const bf16x8*)&Alds[(((mt * 2 + ks) * 4 + q) * 16 + c) * 8];
#pragma unroll
            for (int nt = 0; nt < 2; nt++) {
                int ntg = wave * 2 + nt;
                bfr[nt] = *(const bf16x8*)&Blds[(((ntg * 2 + ks) * 4 + q) * 16 + c) * 8];
            }
#pragma unroll
            for (int mt = 0; mt < 4; mt++)
#pragma unroll
                for (int nt = 0; nt < 2; nt++)
                    acc[mt][nt] = mfma16(af[mt], bfr[nt], acc[mt][nt]);
        }
    }

    // epilogue: co = m0+mt*16+q*4+reg ; s = n0+wave*32+nt*16+c
#pragma unroll
    for (int mt = 0; mt < 4; mt++) {
        int co0 = m0 + mt * 16 + q * 4;
        float b0 = bias[co0 + 0], b1 = bias[co0 + 1];
        float b2 = bias[co0 + 2], b3 = bias[co0 + 3];
#pragma unroll
        for (int nt = 0; nt < 2; nt++) {
            int scol = n0 + wave * 32 + nt * 16 + c;
            float v0 = (acc[mt][nt][0] + b0) * scale;
            float v1 = (acc[mt][nt][1] + b1) * scale;
            float v2 = (acc[mt][nt][2] + b2) * scale;
            float v3 = (acc[mt][nt][3] + b3) * scale;
            if (mode == 0) {
                uint2 pv; pv.x = pack2(v0, v1); pv.y = pack2(v2, v3);
                size_t idx = ((size_t)(b * 8 + (co0 >> 6)) * 4096 + scol) * 64 + (co0 & 63);
                *(uint2*)&((u16*)out)[idx] = pv;
            } else if (mode == 1) {
                u16* o = (u16*)out;
                o[((size_t)(b * 512 + co0 + 0)) * 4096 + scol] = f2bf(v0);
                o[((size_t)(b * 512 + co0 + 1)) * 4096 + scol] = f2bf(v1);
                o[((size_t)(b * 512 + co0 + 2)) * 4096 + scol] = f2bf(v2);
                o[((size_t)(b * 512 + co0 + 3)) * 4096 + scol] = f2bf(v3);
            } else {
                float* o = (float*)out;
                o[((size_t)(b * 512 + co0 + 0)) * 4096 + scol] = v0;
                o[((size_t)(b * 512 + co0 + 1)) * 4096 + scol] = v1;
                o[((size_t)(b * 512 + co0 + 2)) * 4096 + scol] = v2;
                o[((size_t)(b * 512 + co0 + 3)) * 4096 + scol] = v3;
            }
        }
    }
}

// fused Q/K/V projection: blockIdx.z in [0,6): j = z>>1 (0=Q,1=K,2=V), b = z&1
// Q is pre-scaled by log2(e)/8 so attention scores are in the exp2 domain.
__global__ __launch_bounds__(256) void qkv_kernel(const u16* __restrict__ Wbf,
                                                  const float* __restrict__ bq,
                                                  const float* __restrict__ bk,
                                                  const float* __restrict__ bv,
                                                  const u16* __restrict__ tok,
                                                  u16* __restrict__ Qb,
                                                  u16* __restrict__ Kb,
                                                  u16* __restrict__ Vb) {
    __shared__ u16 Alds[4096];    // 8KB
    __shared__ u16 Blds[8192];    // 16KB
    const int z = blockIdx.z, j = z >> 1, b = z & 1;
    const u16* W = Wbf + (size_t)j * 262144;
    const float* bias = (j == 0) ? bq : (j == 1) ? bk : bv;
    void* out = (j == 0) ? (void*)Qb : (j == 1) ? (void*)Kb : (void*)Vb;
    const float scale = (j == 0) ? 0.1803368801f : 1.0f;   // log2(e)/8
    const int mode = (j == 2) ? 1 : 0;
    proj_core(W, bias, tok + (size_t)b * (4096 * 512), out, b, mode, scale, Alds, Blds);
}

// final projection: blockIdx.z = batch, f32 output
__global__ __launch_bounds__(256) void projp_kernel(const u16* __restrict__ Wp,
                                                    const float* __restrict__ bp,
                                                    const u16* __restrict__ attout,
                                                    float* __restrict__ out) {
    __shared__ u16 Alds[4096];
    __shared__ u16 Blds[8192];
    const int b = blockIdx.z;
    proj_core(Wp, bp, attout + (size_t)b * (4096 * 512), out, b, 2, 1.0f, Alds, Blds);
}

// ---------------------------------------------------------------------------
// 3) Flash attention, fixed-base softmax, BARRIER-FREE.
//    Q[bhd][s][64], K[bhd][t][64], VT[bhd][64][t] (all bf16).
//    BM=128 (4 waves x 32 s-cols), BN=64 t-tiles. K and V MFMA A-fragments
//    are loaded straight from global (16B/lane; L1/L2 serve the 4x wave and
//    32x WG reuse) -- no LDS staging, hence NO __syncthreads anywhere.
//    LDS holds only the P^T lane-shuffle, which is intra-wave (same wave
//    writes and reads its own 32 rows; ordering via lgkmcnt, compiler-done).
//    S^T[t][s] tiles -> p=exp2 -> P^T via LDS -> O^T[dv][s] += VT x P^T.
// ---------------------------------------------------------------------------
__global__ __launch_bounds__(256) void attn_kernel(const u16* __restrict__ Qm,
                                                   const u16* __restrict__ Km,
                                                   const u16* __restrict__ Vm,
                                                   u16* __restrict__ attout) {
    __shared__ u16 Plds[128 * 72];    // [s_local][72] padded, 18KB (16B rows)
    const int tid = threadIdx.x, wave = tid >> 6, lane = tid & 63;
    const int q = lane >> 4, c = lane & 15;
    const int bhd = blockIdx.y, s0 = blockIdx.x * 128;
    const u16* Qb = Qm + (size_t)bhd * (4096 * 64);
    const u16* Kb = Km + (size_t)bhd * (4096 * 64);
    const u16* Vb = Vm + (size_t)bhd * (64 * 4096);

    // Q B-frags, held in registers the whole kernel (Q pre-scaled by log2e/8)
    bf16x8 qf[2][2];
#pragma unroll
    for (int st = 0; st < 2; st++)
#pragma unroll
        for (int kd = 0; kd < 2; kd++)
            qf[st][kd] = *(const bf16x8*)
                &Qb[(size_t)(s0 + wave * 32 + st * 16 + c) * 64 + kd * 32 + q * 8];

    // per-lane invariant pieces of the frag addresses
    const u16* Kfb = Kb + (size_t)c * 64 + q * 8;          // + t0*64 later (+tt*1024, +kd*32)
    const u16* Vfb = Vb + (size_t)c * 4096 + q * 8;        // + t0 later (+dt*65536, +kt*32)
    u16* Prow = &Plds[(size_t)(wave * 32 + c) * 72];       // + st*16*72

    f32x4 oacc[4][2] = {};            // [dt][st]: O^T rows dv, cols s
    float lsum[2] = {0.f, 0.f};

    for (int t0 = 0; t0 < 4096; t0 += 64) {
        // K frags direct from global: ka[kd][tt] = K row (t0+tt*16+c), k kd*32+q*8
        bf16x8 ka[2][4];
#pragma unroll
        for (int kd = 0; kd < 2; kd++)
#pragma unroll
            for (int tt = 0; tt < 4; tt++)
                ka[kd][tt] = *(const bf16x8*)&Kfb[(size_t)(t0 + tt * 16) * 64 + kd * 32];
        // V frags direct from global: va[kt][dt] = VT row (dt*16+c), t t0+kt*32+q*8
        bf16x8 va[2][4];
#pragma unroll
        for (int kt = 0; kt < 2; kt++)
#pragma unroll
            for (int dt = 0; dt < 4; dt++)
                va[kt][dt] = *(const bf16x8*)&Vfb[(size_t)(dt * 16) * 4096 + t0 + kt * 32];

        // S^T tile: rows t (4 tiles), cols s (wave's 2 tiles)
        f32x4 sacc[4][2] = {};
#pragma unroll
        for (int kd = 0; kd < 2; kd++)
#pragma unroll
            for (int tt = 0; tt < 4; tt++)
#pragma unroll
                for (int st = 0; st < 2; st++)
                    sacc[tt][st] = mfma16(ka[kd][tt], qf[st][kd], sacc[tt][st]);

        // p = exp2(score); accumulate denominator per-lane; pack P^T -> LDS
#pragma unroll
        for (int st = 0; st < 2; st++) {
#pragma unroll
            for (int tt = 0; tt < 4; tt++) {
                float p0 = fexp2(sacc[tt][st][0]);
                float p1 = fexp2(sacc[tt][st][1]);
                float p2 = fexp2(sacc[tt][st][2]);
                float p3 = fexp2(sacc[tt][st][3]);
                lsum[st] += (p0 + p1) + (p2 + p3);
                uint2 pv; pv.x = pack2(p0, p1); pv.y = pack2(p2, p3);
                *(uint2*)&Prow[st * (16 * 72) + tt * 16 + q * 4] = pv;
            }
        }
        // (same-wave lgkmcnt ordering; no barrier needed)

        // O^T += VT x P^T  (A = VT rows dv, B = Plds rows s; k = t)
#pragma unroll
        for (int kt = 0; kt < 2; kt++) {
            bf16x8 pb[2];
#pragma unroll
            for (int st = 0; st < 2; st++)
                pb[st] = *(const bf16x8*)&Prow[st * (16 * 72) + kt * 32 + q * 8];
#pragma unroll
            for (int dt = 0; dt < 4; dt++)
#pragma unroll
                for (int st = 0; st < 2; st++)
                    oacc[dt][st] = mfma16(va[kt][dt], pb[st], oacc[dt][st]);
        }
    }

    // epilogue: attout[b][s][hd*64+dv]
    const int b = bhd >> 3, hd = bhd & 7;
#pragma unroll
    for (int st = 0; st < 2; st++) {
        float l = lsum[st];
        l += __shfl_xor(l, 16, 64);
        l += __shfl_xor(l, 32, 64);
        float rl = 1.0f / l;
        int s = s0 + wave * 32 + st * 16 + c;
#pragma unroll
        for (int dt = 0; dt < 4; dt++) {
            uint2 pv;
            pv.x = pack2(oacc[dt][st][0] * rl, oacc[dt][st][1] * rl);
            pv.y = pack2(oacc[dt][st][2] * rl, oacc[dt][st][3] * rl);
            size_t idx = ((size_t)(b * 4096 + s)) * 512 + hd * 64 + dt * 16 + q * 4;
            *(uint2*)&attout[idx] = pv;
        }
    }
}

// ---------------------------------------------------------------------------
extern "C" void kernel_launch(void* const* d_in, const int* in_sizes, int n_in,
                              void* d_out, int out_size, void* d_ws, size_t ws_size,
                              hipStream_t stream) {
    (void)in_sizes; (void)n_in; (void)out_size; (void)ws_size;
    const float* x  = (const float*)d_in[0];
    const float* Wq = (const float*)d_in[1];
    const float* bq = (const float*)d_in[2];
    const float* Wk = (const float*)d_in[3];
    const float* bk = (const float*)d_in[4];
    const float* Wv = (const float*)d_in[5];
    const float* bv = (const float*)d_in[6];
    const float* Wp = (const float*)d_in[7];
    const float* bp = (const float*)d_in[8];
    float* out = (float*)d_out;

    const size_t NTOK = (size_t)4 * 1024 * 1024;  // 2*4096*512 elements
    u16* tok = (u16*)d_ws;        // [2][4096][512] bf16; reused as attout later
    u16* Qb  = tok + NTOK;        // [16][4096][64]  (pre-scaled by log2e/8)
    u16* Kb  = Qb + NTOK;         // [16][4096][64]
    u16* Vb  = Kb + NTOK;         // [16][64][4096]
    u16* Wbf = Vb + NTOK;         // [4][512][512] bf16 (q,k,v,p)
    u16* attout = tok;            // alias: tok dead after V projection

    convert_w_kernel<<<dim3(256, 4), 256, 0, stream>>>(Wq, Wk, Wv, Wp, Wbf);
    transpose_kernel<<<dim3(64, 8, 2), 256, 0, stream>>>(x, tok);
    qkv_kernel<<<dim3(32, 8, 6), 256, 0, stream>>>(Wbf, bq, bk, bv, tok, Qb, Kb, Vb);
    attn_kernel<<<dim3(32, 16), 256, 0, stream>>>(Qb, Kb, Vb, attout);
    projp_kernel<<<dim3(32, 8, 2), 256, 0, stream>>>(Wbf + 3 * 262144, bp, attout, out);
}

// Round 6
// 242.753 us; speedup vs baseline: 1.5645x; 1.5129x over previous
//
#include <hip/hip_runtime.h>
#include <stdint.h>
#include <math.h>

typedef unsigned short u16;
typedef uint32_t u32;
typedef short bf16x8 __attribute__((ext_vector_type(8)));   // 8 bf16 = 4 VGPRs
typedef float f32x4  __attribute__((ext_vector_type(4)));

#define DEV __device__ __forceinline__

DEV u16 f2bf(float f) {
    union { float f; u32 u; } x; x.f = f;
    u32 lsb = (x.u >> 16) & 1u;
    x.u += 0x7fffu + lsb;            // RNE
    return (u16)(x.u >> 16);
}

// pack two f32 -> two bf16 (round-half-up) in 3 VALU ops
DEV u32 pack2(float a, float b) {
    union { float f; u32 u; } x, y; x.f = a; y.f = b;
    return __builtin_amdgcn_perm(y.u + 0x8000u, x.u + 0x8000u, 0x07060302u);
}

#if __has_builtin(__builtin_amdgcn_exp2f)
DEV float fexp2(float x) { return __builtin_amdgcn_exp2f(x); }
#else
DEV float fexp2(float x) { return __expf(x * 0.69314718056f); }
#endif

DEV f32x4 mfma16(bf16x8 a, bf16x8 b, f32x4 c) {
    return __builtin_amdgcn_mfma_f32_16x16x32_bf16(a, b, c, 0, 0, 0);
}

// ---------------------------------------------------------------------------
// 0) Convert the four f32 weight matrices to bf16: dst[j][co][ci], j=q,k,v,p
// ---------------------------------------------------------------------------
__global__ __launch_bounds__(256) void convert_w_kernel(const float* __restrict__ w0,
                                                        const float* __restrict__ w1,
                                                        const float* __restrict__ w2,
                                                        const float* __restrict__ w3,
                                                        u16* __restrict__ dst) {
    const float* src = (blockIdx.y == 0) ? w0 : (blockIdx.y == 1) ? w1
                     : (blockIdx.y == 2) ? w2 : w3;
    int idx = (blockIdx.x * 256 + threadIdx.x) * 4;   // over 512*512 = 262144
    float4 v = *(const float4*)&src[idx];
    uint2 pv;
    pv.x = pack2(v.x, v.y);
    pv.y = pack2(v.z, v.w);
    *(uint2*)&dst[(size_t)blockIdx.y * 262144 + idx] = pv;
}

// ---------------------------------------------------------------------------
// 1) Transpose+convert x[b][c][s] (f32) -> tok[b][s][c] (bf16)   C=512, S=4096
// ---------------------------------------------------------------------------
__global__ __launch_bounds__(256) void transpose_kernel(const float* __restrict__ x,
                                                        u16* __restrict__ tok) {
    __shared__ u16 t[64][65];
    const int b = blockIdx.z, c0 = blockIdx.y * 64, s0 = blockIdx.x * 64;
    const float* xb = x + ((size_t)b * 512 + c0) * 4096 + s0;
    u16* tb = tok + ((size_t)b * 4096 + s0) * 512 + c0;
    const int tid = threadIdx.x;
    {   // read: 64 rows (c) x 16 float4 cols (s)
        const int jc = tid & 15, i0 = tid >> 4;
#pragma unroll
        for (int ii = 0; ii < 4; ii++) {
            int i = i0 * 4 + ii;
            float4 v = *(const float4*)&xb[(size_t)i * 4096 + jc * 4];
            t[i][jc * 4 + 0] = f2bf(v.x);
            t[i][jc * 4 + 1] = f2bf(v.y);
            t[i][jc * 4 + 2] = f2bf(v.z);
            t[i][jc * 4 + 3] = f2bf(v.w);
        }
    }
    __syncthreads();
    {   // write: 64 rows (s) x 32 u32 cols (c pairs)
        const int j = tid & 31, i0 = tid >> 5;
#pragma unroll
        for (int ii = 0; ii < 8; ii++) {
            int srow = i0 * 8 + ii;
            u32 v = (u32)t[j * 2][srow] | ((u32)t[j * 2 + 1][srow] << 16);
            *(u32*)(&tb[(size_t)srow * 512 + j * 2]) = v;
        }
    }
}

// ---------------------------------------------------------------------------
// 2) Projection GEMM core: out[co][s] = (sum_c W[co][c]*Bb[s][c] + bias[co])*scale
//    M-tile 64 (co), N-tile 128 (s), BK=64, 4 waves (wave owns 32 n-cols).
//    LDS frag order: granule(rt,ks,q,r) -> 16B of row rt*16+r, k ks*32+q*8.
//    mode 0: out bf16 [b][hd][s][d]   mode 1: out bf16 [b*512+co][s]
//    mode 2: out f32  [b*512+co][s]
// ---------------------------------------------------------------------------
DEV void proj_core(const u16* __restrict__ W, const float* __restrict__ bias,
                   const u16* __restrict__ Bb, void* __restrict__ out,
                   int b, int mode, float scale,
                   u16* __restrict__ Alds, u16* __restrict__ Blds) {
    const int tid = threadIdx.x;
    const int wave = tid >> 6, lane = tid & 63, q = lane >> 4, c = lane & 15;
    const int m0 = blockIdx.y * 64, n0 = blockIdx.x * 128;

    f32x4 acc[4][2] = {};

    for (int k0 = 0; k0 < 512; k0 += 64) {
        __syncthreads();
#pragma unroll
        for (int i = 0; i < 2; i++) {   // A: 512 granules (64x64), 2/thread
            int g = tid + i * 256;
            int r = g & 15, qq = (g >> 4) & 3, ks = (g >> 6) & 1, rt = g >> 7;
            int col = k0 + ks * 32 + qq * 8;
            *(int4*)&Alds[g * 8] = *(const int4*)&W[(size_t)(m0 + rt * 16 + r) * 512 + col];
        }
#pragma unroll
        for (int i = 0; i < 4; i++) {   // B: 1024 granules (128x64), 4/thread
            int g = tid + i * 256;
            int r = g & 15, qq = (g >> 4) & 3, ks = (g >> 6) & 1, rt = g >> 7;
            int col = k0 + ks * 32 + qq * 8;
            *(int4*)&Blds[g * 8] = *(const int4*)&Bb[(size_t)(n0 + rt * 16 + r) * 512 + col];
        }
        __syncthreads();
#pragma unroll
        for (int ks = 0; ks < 2; ks++) {
            bf16x8 af[4], bfr[2];
#pragma unroll
            for (int mt = 0; mt < 4; mt++)
                af[mt] = *(const bf16x8*)&Alds[(((mt * 2 + ks) * 4 + q) * 16 + c) * 8];
#pragma unroll
            for (int nt = 0; nt < 2; nt++) {
                int ntg = wave * 2 + nt;
                bfr[nt] = *(const bf16x8*)&Blds[(((ntg * 2 + ks) * 4 + q) * 16 + c) * 8];
            }
#pragma unroll
            for (int mt = 0; mt < 4; mt++)
#pragma unroll
                for (int nt = 0; nt < 2; nt++)
                    acc[mt][nt] = mfma16(af[mt], bfr[nt], acc[mt][nt]);
        }
    }

    // epilogue: co = m0+mt*16+q*4+reg ; s = n0+wave*32+nt*16+c
#pragma unroll
    for (int mt = 0; mt < 4; mt++) {
        int co0 = m0 + mt * 16 + q * 4;
        float b0 = bias[co0 + 0], b1 = bias[co0 + 1];
        float b2 = bias[co0 + 2], b3 = bias[co0 + 3];
#pragma unroll
        for (int nt = 0; nt < 2; nt++) {
            int scol = n0 + wave * 32 + nt * 16 + c;
            float v0 = (acc[mt][nt][0] + b0) * scale;
            float v1 = (acc[mt][nt][1] + b1) * scale;
            float v2 = (acc[mt][nt][2] + b2) * scale;
            float v3 = (acc[mt][nt][3] + b3) * scale;
            if (mode == 0) {
                uint2 pv; pv.x = pack2(v0, v1); pv.y = pack2(v2, v3);
                size_t idx = ((size_t)(b * 8 + (co0 >> 6)) * 4096 + scol) * 64 + (co0 & 63);
                *(uint2*)&((u16*)out)[idx] = pv;
            } else if (mode == 1) {
                u16* o = (u16*)out;
                o[((size_t)(b * 512 + co0 + 0)) * 4096 + scol] = f2bf(v0);
                o[((size_t)(b * 512 + co0 + 1)) * 4096 + scol] = f2bf(v1);
                o[((size_t)(b * 512 + co0 + 2)) * 4096 + scol] = f2bf(v2);
                o[((size_t)(b * 512 + co0 + 3)) * 4096 + scol] = f2bf(v3);
            } else {
                float* o = (float*)out;
                o[((size_t)(b * 512 + co0 + 0)) * 4096 + scol] = v0;
                o[((size_t)(b * 512 + co0 + 1)) * 4096 + scol] = v1;
                o[((size_t)(b * 512 + co0 + 2)) * 4096 + scol] = v2;
                o[((size_t)(b * 512 + co0 + 3)) * 4096 + scol] = v3;
            }
        }
    }
}

// fused Q/K/V projection: blockIdx.z in [0,6): j = z>>1 (0=Q,1=K,2=V), b = z&1
// Q is pre-scaled by log2(e)/8 so attention scores are in the exp2 domain.
__global__ __launch_bounds__(256) void qkv_kernel(const u16* __restrict__ Wbf,
                                                  const float* __restrict__ bq,
                                                  const float* __restrict__ bk,
                                                  const float* __restrict__ bv,
                                                  const u16* __restrict__ tok,
                                                  u16* __restrict__ Qb,
                                                  u16* __restrict__ Kb,
                                                  u16* __restrict__ Vb) {
    __shared__ u16 Alds[4096];    // 8KB
    __shared__ u16 Blds[8192];    // 16KB
    const int z = blockIdx.z, j = z >> 1, b = z & 1;
    const u16* W = Wbf + (size_t)j * 262144;
    const float* bias = (j == 0) ? bq : (j == 1) ? bk : bv;
    void* out = (j == 0) ? (void*)Qb : (j == 1) ? (void*)Kb : (void*)Vb;
    const float scale = (j == 0) ? 0.1803368801f : 1.0f;   // log2(e)/8
    const int mode = (j == 2) ? 1 : 0;
    proj_core(W, bias, tok + (size_t)b * (4096 * 512), out, b, mode, scale, Alds, Blds);
}

// final projection: blockIdx.z = batch, f32 output
__global__ __launch_bounds__(256) void projp_kernel(const u16* __restrict__ Wp,
                                                    const float* __restrict__ bp,
                                                    const u16* __restrict__ attout,
                                                    float* __restrict__ out) {
    __shared__ u16 Alds[4096];
    __shared__ u16 Blds[8192];
    const int b = blockIdx.z;
    proj_core(Wp, bp, attout + (size_t)b * (4096 * 512), out, b, 2, 1.0f, Alds, Blds);
}

// ---------------------------------------------------------------------------
// 3) Flash attention, fixed-base softmax, DOUBLE-BUFFERED K/V staging with a
//    single barrier per iteration. Q[bhd][s][64], K[bhd][t][64], VT[bhd][64][t].
//    BM=128 (4 waves x 32 s-cols), BN=64 t-tiles. Per iter: (1) issue next
//    tile's global loads into VGPRs, (2) compute on current LDS buffer
//    (loads land under ~700cyc of MFMA/exp), (3) ds_write staged regs into
//    the other buffer, (4) one __syncthreads. P^T shuffle is intra-wave
//    (no barrier; validated in R5).
// ---------------------------------------------------------------------------
__global__ __launch_bounds__(256) void attn_kernel(const u16* __restrict__ Qm,
                                                   const u16* __restrict__ Km,
                                                   const u16* __restrict__ Vm,
                                                   u16* __restrict__ attout) {
    __shared__ u16 Klds[2][4096];     // 2 x 8KB, frag order (t4,kk,qq,r)
    __shared__ u16 Vlds[2][4096];     // 2 x 8KB, frag order (t4,kk,qq,r)
    __shared__ u16 Plds[128 * 72];    // [s_local][72] padded, 18KB (16B rows)
    const int tid = threadIdx.x, wave = tid >> 6, lane = tid & 63;
    const int q = lane >> 4, c = lane & 15;
    const int bhd = blockIdx.y, s0 = blockIdx.x * 128;
    const u16* Qb = Qm + (size_t)bhd * (4096 * 64);
    const u16* Kb = Km + (size_t)bhd * (4096 * 64);
    const u16* Vb = Vm + (size_t)bhd * (64 * 4096);

    // Q B-frags, held in registers the whole kernel (Q pre-scaled by log2e/8)
    bf16x8 qf[2][2];
#pragma unroll
    for (int st = 0; st < 2; st++)
#pragma unroll
        for (int kd = 0; kd < 2; kd++)
            qf[st][kd] = *(const bf16x8*)
                &Qb[(size_t)(s0 + wave * 32 + st * 16 + c) * 64 + kd * 32 + q * 8];

    // staging: this thread owns granules g0=tid (t4 in 0..1) and g1=tid+256
    // (t4 in 2..3); r/qq/kk identical for both. K granule g <- row
    // (t0+t4*16+r), k-chunk kk*32+qq*8 ; V granule g <- VT row (t4*16+r),
    // t-offset t0+kk*32+qq*8.
    const int rr = tid & 15, qq = (tid >> 4) & 3, kk = (tid >> 6) & 1;
    const int t40 = tid >> 7, t41 = t40 + 2;
    const u16* Ksrc0 = Kb + (size_t)(t40 * 16 + rr) * 64 + kk * 32 + qq * 8;  // + t0*64
    const u16* Ksrc1 = Kb + (size_t)(t41 * 16 + rr) * 64 + kk * 32 + qq * 8;
    const u16* Vsrc0 = Vb + (size_t)(t40 * 16 + rr) * 4096 + kk * 32 + qq * 8; // + t0
    const u16* Vsrc1 = Vb + (size_t)(t41 * 16 + rr) * 4096 + kk * 32 + qq * 8;
    u16* Prow = &Plds[(size_t)(wave * 32 + c) * 72];       // + st*16*72

    f32x4 oacc[4][2] = {};            // [dt][st]: O^T rows dv, cols s
    float lsum[2] = {0.f, 0.f};

    // prologue: stage tile 0 into buffer 0
    *(int4*)&Klds[0][tid * 8]         = *(const int4*)&Ksrc0[0];
    *(int4*)&Klds[0][(tid + 256) * 8] = *(const int4*)&Ksrc1[0];
    *(int4*)&Vlds[0][tid * 8]         = *(const int4*)&Vsrc0[0];
    *(int4*)&Vlds[0][(tid + 256) * 8] = *(const int4*)&Vsrc1[0];
    __syncthreads();

    for (int it = 0; it < 64; it++) {
        const int p = it & 1;
        const size_t t0n = (size_t)(((it + 1) & 63) * 64);  // next tile (wraps; harmless)

        // (1) issue next-tile global loads into VGPRs (land under compute)
        int4 kst0 = *(const int4*)&Ksrc0[t0n * 64];
        int4 kst1 = *(const int4*)&Ksrc1[t0n * 64];
        int4 vst0 = *(const int4*)&Vsrc0[t0n];
        int4 vst1 = *(const int4*)&Vsrc1[t0n];

        // (2) compute on buffer p
        // S^T tile: rows t (4 tiles), cols s (wave's 2 tiles)
        f32x4 sacc[4][2] = {};
#pragma unroll
        for (int kd = 0; kd < 2; kd++) {
            bf16x8 ka[4];
#pragma unroll
            for (int tt = 0; tt < 4; tt++)
                ka[tt] = *(const bf16x8*)&Klds[p][(((tt * 2 + kd) * 4 + q) * 16 + c) * 8];
#pragma unroll
            for (int tt = 0; tt < 4; tt++)
#pragma unroll
                for (int st = 0; st < 2; st++)
                    sacc[tt][st] = mfma16(ka[tt], qf[st][kd], sacc[tt][st]);
        }

        // p = exp2(score); accumulate denominator per-lane; pack P^T -> LDS
#pragma unroll
        for (int st = 0; st < 2; st++) {
#pragma unroll
            for (int tt = 0; tt < 4; tt++) {
                float p0 = fexp2(sacc[tt][st][0]);
                float p1 = fexp2(sacc[tt][st][1]);
                float p2 = fexp2(sacc[tt][st][2]);
                float p3 = fexp2(sacc[tt][st][3]);
                lsum[st] += (p0 + p1) + (p2 + p3);
                uint2 pv; pv.x = pack2(p0, p1); pv.y = pack2(p2, p3);
                *(uint2*)&Prow[st * (16 * 72) + tt * 16 + q * 4] = pv;
            }
        }
        // (same-wave lgkmcnt ordering for P; no barrier needed)

        // O^T += VT x P^T  (A = VT rows dv, B = Plds rows s; k = t)
#pragma unroll
        for (int kt = 0; kt < 2; kt++) {
            bf16x8 va[4], pb[2];
#pragma unroll
            for (int dt = 0; dt < 4; dt++)
                va[dt] = *(const bf16x8*)&Vlds[p][(((dt * 2 + kt) * 4 + q) * 16 + c) * 8];
#pragma unroll
            for (int st = 0; st < 2; st++)
                pb[st] = *(const bf16x8*)&Prow[st * (16 * 72) + kt * 32 + q * 8];
#pragma unroll
            for (int dt = 0; dt < 4; dt++)
#pragma unroll
                for (int st = 0; st < 2; st++)
                    oacc[dt][st] = mfma16(va[kt == 0 ? dt : dt], pb[st], oacc[dt][st]);
        }

        // (3) write staged regs into the other buffer; (4) single barrier
        *(int4*)&Klds[1 - p][tid * 8]         = kst0;
        *(int4*)&Klds[1 - p][(tid + 256) * 8] = kst1;
        *(int4*)&Vlds[1 - p][tid * 8]         = vst0;
        *(int4*)&Vlds[1 - p][(tid + 256) * 8] = vst1;
        __syncthreads();
    }

    // epilogue: attout[b][s][hd*64+dv]
    const int b = bhd >> 3, hd = bhd & 7;
#pragma unroll
    for (int st = 0; st < 2; st++) {
        float l = lsum[st];
        l += __shfl_xor(l, 16, 64);
        l += __shfl_xor(l, 32, 64);
        float rl = 1.0f / l;
        int s = s0 + wave * 32 + st * 16 + c;
#pragma unroll
        for (int dt = 0; dt < 4; dt++) {
            uint2 pv;
            pv.x = pack2(oacc[dt][st][0] * rl, oacc[dt][st][1] * rl);
            pv.y = pack2(oacc[dt][st][2] * rl, oacc[dt][st][3] * rl);
            size_t idx = ((size_t)(b * 4096 + s)) * 512 + hd * 64 + dt * 16 + q * 4;
            *(uint2*)&attout[idx] = pv;
        }
    }
}

// ---------------------------------------------------------------------------
extern "C" void kernel_launch(void* const* d_in, const int* in_sizes, int n_in,
                              void* d_out, int out_size, void* d_ws, size_t ws_size,
                              hipStream_t stream) {
    (void)in_sizes; (void)n_in; (void)out_size; (void)ws_size;
    const float* x  = (const float*)d_in[0];
    const float* Wq = (const float*)d_in[1];
    const float* bq = (const float*)d_in[2];
    const float* Wk = (const float*)d_in[3];
    const float* bk = (const float*)d_in[4];
    const float* Wv = (const float*)d_in[5];
    const float* bv = (const float*)d_in[6];
    const float* Wp = (const float*)d_in[7];
    const float* bp = (const float*)d_in[8];
    float* out = (float*)d_out;

    const size_t NTOK = (size_t)4 * 1024 * 1024;  // 2*4096*512 elements
    u16* tok = (u16*)d_ws;        // [2][4096][512] bf16; reused as attout later
    u16* Qb  = tok + NTOK;        // [16][4096][64]  (pre-scaled by log2e/8)
    u16* Kb  = Qb + NTOK;         // [16][4096][64]
    u16* Vb  = Kb + NTOK;         // [16][64][4096]
    u16* Wbf = Vb + NTOK;         // [4][512][512] bf16 (q,k,v,p)
    u16* attout = tok;            // alias: tok dead after V projection

    convert_w_kernel<<<dim3(256, 4), 256, 0, stream>>>(Wq, Wk, Wv, Wp, Wbf);
    transpose_kernel<<<dim3(64, 8, 2), 256, 0, stream>>>(x, tok);
    qkv_kernel<<<dim3(32, 8, 6), 256, 0, stream>>>(Wbf, bq, bk, bv, tok, Qb, Kb, Vb);
    attn_kernel<<<dim3(32, 16), 256, 0, stream>>>(Qb, Kb, Vb, attout);
    projp_kernel<<<dim3(32, 8, 2), 256, 0, stream>>>(Wbf + 3 * 262144, bp, attout, out);
}

// Round 7
// 232.947 us; speedup vs baseline: 1.6304x; 1.0421x over previous
//
#include <hip/hip_runtime.h>
#include <stdint.h>
#include <math.h>

typedef unsigned short u16;
typedef uint32_t u32;
typedef short bf16x8 __attribute__((ext_vector_type(8)));   // 8 bf16 = 4 VGPRs
typedef float f32x4  __attribute__((ext_vector_type(4)));

#define DEV __device__ __forceinline__

DEV u16 f2bf(float f) {
    union { float f; u32 u; } x; x.f = f;
    u32 lsb = (x.u >> 16) & 1u;
    x.u += 0x7fffu + lsb;            // RNE
    return (u16)(x.u >> 16);
}

// pack two f32 -> two bf16 (round-half-up) in 3 VALU ops
DEV u32 pack2(float a, float b) {
    union { float f; u32 u; } x, y; x.f = a; y.f = b;
    return __builtin_amdgcn_perm(y.u + 0x8000u, x.u + 0x8000u, 0x07060302u);
}

#if __has_builtin(__builtin_amdgcn_exp2f)
DEV float fexp2(float x) { return __builtin_amdgcn_exp2f(x); }
#else
DEV float fexp2(float x) { return __expf(x * 0.69314718056f); }
#endif

DEV f32x4 mfma16(bf16x8 a, bf16x8 b, f32x4 c) {
    return __builtin_amdgcn_mfma_f32_16x16x32_bf16(a, b, c, 0, 0, 0);
}

// ---------------------------------------------------------------------------
// 0) Convert the four f32 weight matrices to bf16: dst[j][co][ci], j=q,k,v,p
// ---------------------------------------------------------------------------
__global__ __launch_bounds__(256) void convert_w_kernel(const float* __restrict__ w0,
                                                        const float* __restrict__ w1,
                                                        const float* __restrict__ w2,
                                                        const float* __restrict__ w3,
                                                        u16* __restrict__ dst) {
    const float* src = (blockIdx.y == 0) ? w0 : (blockIdx.y == 1) ? w1
                     : (blockIdx.y == 2) ? w2 : w3;
    int idx = (blockIdx.x * 256 + threadIdx.x) * 4;   // over 512*512 = 262144
    float4 v = *(const float4*)&src[idx];
    uint2 pv;
    pv.x = pack2(v.x, v.y);
    pv.y = pack2(v.z, v.w);
    *(uint2*)&dst[(size_t)blockIdx.y * 262144 + idx] = pv;
}

// ---------------------------------------------------------------------------
// 1) Transpose+convert x[b][c][s] (f32) -> tok[b][s][c] (bf16)   C=512, S=4096
// ---------------------------------------------------------------------------
__global__ __launch_bounds__(256) void transpose_kernel(const float* __restrict__ x,
                                                        u16* __restrict__ tok) {
    __shared__ u16 t[64][65];
    const int b = blockIdx.z, c0 = blockIdx.y * 64, s0 = blockIdx.x * 64;
    const float* xb = x + ((size_t)b * 512 + c0) * 4096 + s0;
    u16* tb = tok + ((size_t)b * 4096 + s0) * 512 + c0;
    const int tid = threadIdx.x;
    {   // read: 64 rows (c) x 16 float4 cols (s)
        const int jc = tid & 15, i0 = tid >> 4;
#pragma unroll
        for (int ii = 0; ii < 4; ii++) {
            int i = i0 * 4 + ii;
            float4 v = *(const float4*)&xb[(size_t)i * 4096 + jc * 4];
            t[i][jc * 4 + 0] = f2bf(v.x);
            t[i][jc * 4 + 1] = f2bf(v.y);
            t[i][jc * 4 + 2] = f2bf(v.z);
            t[i][jc * 4 + 3] = f2bf(v.w);
        }
    }
    __syncthreads();
    {   // write: 64 rows (s) x 32 u32 cols (c pairs)
        const int j = tid & 31, i0 = tid >> 5;
#pragma unroll
        for (int ii = 0; ii < 8; ii++) {
            int srow = i0 * 8 + ii;
            u32 v = (u32)t[j * 2][srow] | ((u32)t[j * 2 + 1][srow] << 16);
            *(u32*)(&tb[(size_t)srow * 512 + j * 2]) = v;
        }
    }
}

// ---------------------------------------------------------------------------
// 2) Projection GEMM core, DOUBLE-BUFFERED (R6 attn structure): 128x128 tile,
//    BK=32, 16 K-steps, ONE barrier per step. Per step: (1) issue next
//    K-chunk global loads into VGPRs, (2) 8 ds_read_b128 + 16 MFMA on the
//    current buffer, (3) ds_write staged regs into other buffer, (4) barrier.
//    LDS frag order: granule(mt,q,c) -> 16B of row mt*16+c, k-chunk q*8.
//    4 waves: wave owns (wave&1) m-half x (wave>>1) n-half, 4x4 accs.
//    mode 0: out bf16 [b][hd][s][d]   mode 1: out bf16 [b*512+co][s]
//    mode 2: out f32  [b*512+co][s]
// ---------------------------------------------------------------------------
DEV void proj_core(const u16* __restrict__ W, const float* __restrict__ bias,
                   const u16* __restrict__ Bb, void* __restrict__ out,
                   int b, int mode, float scale,
                   u16 (*__restrict__ Alds)[4096], u16 (*__restrict__ Blds)[4096]) {
    const int tid = threadIdx.x;
    const int wave = tid >> 6, lane = tid & 63, q = lane >> 4, c = lane & 15;
    const int m0 = blockIdx.y * 128, n0 = blockIdx.x * 128;

    // staging: thread owns granules g=tid (mt 0..3) and g+256 (mt 4..7);
    // granule g: c=g&15, q=(g>>4)&3, mt=g>>6 -> row (m0|n0)+mt*16+c, k q*8
    const int cs = tid & 15, qs = (tid >> 4) & 3, ms = (tid >> 6) & 3;
    const u16* Asrc0 = W  + (size_t)(m0 + ms * 16 + cs) * 512 + qs * 8;
    const u16* Asrc1 = W  + (size_t)(m0 + (ms + 4) * 16 + cs) * 512 + qs * 8;
    const u16* Bsrc0 = Bb + (size_t)(n0 + ms * 16 + cs) * 512 + qs * 8;
    const u16* Bsrc1 = Bb + (size_t)(n0 + (ms + 4) * 16 + cs) * 512 + qs * 8;

    f32x4 acc[4][4] = {};

    // prologue: stage k-chunk 0 into buffer 0
    *(int4*)&Alds[0][tid * 8]         = *(const int4*)&Asrc0[0];
    *(int4*)&Alds[0][(tid + 256) * 8] = *(const int4*)&Asrc1[0];
    *(int4*)&Blds[0][tid * 8]         = *(const int4*)&Bsrc0[0];
    *(int4*)&Blds[0][(tid + 256) * 8] = *(const int4*)&Bsrc1[0];
    __syncthreads();

    for (int it = 0; it < 16; it++) {
        const int p = it & 1;
        const int kn = ((it + 1) & 15) * 32;   // next k-chunk (elements; wraps)

        // (1) prefetch next chunk into VGPRs
        int4 ast0 = *(const int4*)&Asrc0[kn];
        int4 ast1 = *(const int4*)&Asrc1[kn];
        int4 bst0 = *(const int4*)&Bsrc0[kn];
        int4 bst1 = *(const int4*)&Bsrc1[kn];

        // (2) compute on buffer p
        bf16x8 af[4], bfr[4];
#pragma unroll
        for (int t = 0; t < 4; t++) {
            int gm = (((wave & 1) * 4 + t) * 4 + q) * 16 + c;
            af[t] = *(const bf16x8*)&Alds[p][gm * 8];
            int gn = (((wave >> 1) * 4 + t) * 4 + q) * 16 + c;
            bfr[t] = *(const bf16x8*)&Blds[p][gn * 8];
        }
#pragma unroll
        for (int mt = 0; mt < 4; mt++)
#pragma unroll
            for (int nt = 0; nt < 4; nt++)
                acc[mt][nt] = mfma16(af[mt], bfr[nt], acc[mt][nt]);

        // (3) write staged regs into the other buffer; (4) one barrier
        *(int4*)&Alds[1 - p][tid * 8]         = ast0;
        *(int4*)&Alds[1 - p][(tid + 256) * 8] = ast1;
        *(int4*)&Blds[1 - p][tid * 8]         = bst0;
        *(int4*)&Blds[1 - p][(tid + 256) * 8] = bst1;
        __syncthreads();
    }

    // epilogue (validated in R2): co = mbase+mt*16+q*4+reg ; s = nbase+nt*16+c
    const int mbase = m0 + (wave & 1) * 64, nbase = n0 + (wave >> 1) * 64;
#pragma unroll
    for (int mt = 0; mt < 4; mt++) {
        int co0 = mbase + mt * 16 + q * 4;
        float b0 = bias[co0 + 0], b1 = bias[co0 + 1];
        float b2 = bias[co0 + 2], b3 = bias[co0 + 3];
#pragma unroll
        for (int nt = 0; nt < 4; nt++) {
            int scol = nbase + nt * 16 + c;
            float v0 = (acc[mt][nt][0] + b0) * scale;
            float v1 = (acc[mt][nt][1] + b1) * scale;
            float v2 = (acc[mt][nt][2] + b2) * scale;
            float v3 = (acc[mt][nt][3] + b3) * scale;
            if (mode == 0) {
                uint2 pv; pv.x = pack2(v0, v1); pv.y = pack2(v2, v3);
                size_t idx = ((size_t)(b * 8 + (co0 >> 6)) * 4096 + scol) * 64 + (co0 & 63);
                *(uint2*)&((u16*)out)[idx] = pv;
            } else if (mode == 1) {
                u16* o = (u16*)out;
                o[((size_t)(b * 512 + co0 + 0)) * 4096 + scol] = f2bf(v0);
                o[((size_t)(b * 512 + co0 + 1)) * 4096 + scol] = f2bf(v1);
                o[((size_t)(b * 512 + co0 + 2)) * 4096 + scol] = f2bf(v2);
                o[((size_t)(b * 512 + co0 + 3)) * 4096 + scol] = f2bf(v3);
            } else {
                float* o = (float*)out;
                o[((size_t)(b * 512 + co0 + 0)) * 4096 + scol] = v0;
                o[((size_t)(b * 512 + co0 + 1)) * 4096 + scol] = v1;
                o[((size_t)(b * 512 + co0 + 2)) * 4096 + scol] = v2;
                o[((size_t)(b * 512 + co0 + 3)) * 4096 + scol] = v3;
            }
        }
    }
}

// fused Q/K/V projection: blockIdx.z in [0,6): j = z>>1 (0=Q,1=K,2=V), b = z&1
// Q is pre-scaled by log2(e)/8 so attention scores are in the exp2 domain.
__global__ __launch_bounds__(256) void qkv_kernel(const u16* __restrict__ Wbf,
                                                  const float* __restrict__ bq,
                                                  const float* __restrict__ bk,
                                                  const float* __restrict__ bv,
                                                  const u16* __restrict__ tok,
                                                  u16* __restrict__ Qb,
                                                  u16* __restrict__ Kb,
                                                  u16* __restrict__ Vb) {
    __shared__ u16 Alds[2][4096];    // 2 x 8KB
    __shared__ u16 Blds[2][4096];    // 2 x 8KB
    const int z = blockIdx.z, j = z >> 1, b = z & 1;
    const u16* W = Wbf + (size_t)j * 262144;
    const float* bias = (j == 0) ? bq : (j == 1) ? bk : bv;
    void* out = (j == 0) ? (void*)Qb : (j == 1) ? (void*)Kb : (void*)Vb;
    const float scale = (j == 0) ? 0.1803368801f : 1.0f;   // log2(e)/8
    const int mode = (j == 2) ? 1 : 0;
    proj_core(W, bias, tok + (size_t)b * (4096 * 512), out, b, mode, scale, Alds, Blds);
}

// final projection: blockIdx.z = batch, f32 output
__global__ __launch_bounds__(256) void projp_kernel(const u16* __restrict__ Wp,
                                                    const float* __restrict__ bp,
                                                    const u16* __restrict__ attout,
                                                    float* __restrict__ out) {
    __shared__ u16 Alds[2][4096];
    __shared__ u16 Blds[2][4096];
    const int b = blockIdx.z;
    proj_core(Wp, bp, attout + (size_t)b * (4096 * 512), out, b, 2, 1.0f, Alds, Blds);
}

// ---------------------------------------------------------------------------
// 3) Flash attention, fixed-base softmax, DOUBLE-BUFFERED K/V staging with a
//    single barrier per iteration (validated R6). Q[bhd][s][64], K[bhd][t][64],
//    VT[bhd][64][t]. BM=128 (4 waves x 32 s-cols), BN=64 t-tiles. P^T shuffle
//    is intra-wave (no barrier).
// ---------------------------------------------------------------------------
__global__ __launch_bounds__(256) void attn_kernel(const u16* __restrict__ Qm,
                                                   const u16* __restrict__ Km,
                                                   const u16* __restrict__ Vm,
                                                   u16* __restrict__ attout) {
    __shared__ u16 Klds[2][4096];     // 2 x 8KB, frag order (t4,kk,qq,r)
    __shared__ u16 Vlds[2][4096];     // 2 x 8KB, frag order (t4,kk,qq,r)
    __shared__ u16 Plds[128 * 72];    // [s_local][72] padded, 18KB (16B rows)
    const int tid = threadIdx.x, wave = tid >> 6, lane = tid & 63;
    const int q = lane >> 4, c = lane & 15;
    const int bhd = blockIdx.y, s0 = blockIdx.x * 128;
    const u16* Qb = Qm + (size_t)bhd * (4096 * 64);
    const u16* Kb = Km + (size_t)bhd * (4096 * 64);
    const u16* Vb = Vm + (size_t)bhd * (64 * 4096);

    // Q B-frags, held in registers the whole kernel (Q pre-scaled by log2e/8)
    bf16x8 qf[2][2];
#pragma unroll
    for (int st = 0; st < 2; st++)
#pragma unroll
        for (int kd = 0; kd < 2; kd++)
            qf[st][kd] = *(const bf16x8*)
                &Qb[(size_t)(s0 + wave * 32 + st * 16 + c) * 64 + kd * 32 + q * 8];

    const int rr = tid & 15, qq = (tid >> 4) & 3, kk = (tid >> 6) & 1;
    const int t40 = tid >> 7, t41 = t40 + 2;
    const u16* Ksrc0 = Kb + (size_t)(t40 * 16 + rr) * 64 + kk * 32 + qq * 8;  // + t0*64
    const u16* Ksrc1 = Kb + (size_t)(t41 * 16 + rr) * 64 + kk * 32 + qq * 8;
    const u16* Vsrc0 = Vb + (size_t)(t40 * 16 + rr) * 4096 + kk * 32 + qq * 8; // + t0
    const u16* Vsrc1 = Vb + (size_t)(t41 * 16 + rr) * 4096 + kk * 32 + qq * 8;
    u16* Prow = &Plds[(size_t)(wave * 32 + c) * 72];       // + st*16*72

    f32x4 oacc[4][2] = {};            // [dt][st]: O^T rows dv, cols s
    float lsum[2] = {0.f, 0.f};

    // prologue: stage tile 0 into buffer 0
    *(int4*)&Klds[0][tid * 8]         = *(const int4*)&Ksrc0[0];
    *(int4*)&Klds[0][(tid + 256) * 8] = *(const int4*)&Ksrc1[0];
    *(int4*)&Vlds[0][tid * 8]         = *(const int4*)&Vsrc0[0];
    *(int4*)&Vlds[0][(tid + 256) * 8] = *(const int4*)&Vsrc1[0];
    __syncthreads();

    for (int it = 0; it < 64; it++) {
        const int p = it & 1;
        const size_t t0n = (size_t)(((it + 1) & 63) * 64);  // next tile (wraps; harmless)

        // (1) issue next-tile global loads into VGPRs (land under compute)
        int4 kst0 = *(const int4*)&Ksrc0[t0n * 64];
        int4 kst1 = *(const int4*)&Ksrc1[t0n * 64];
        int4 vst0 = *(const int4*)&Vsrc0[t0n];
        int4 vst1 = *(const int4*)&Vsrc1[t0n];

        // (2) compute on buffer p
        f32x4 sacc[4][2] = {};
#pragma unroll
        for (int kd = 0; kd < 2; kd++) {
            bf16x8 ka[4];
#pragma unroll
            for (int tt = 0; tt < 4; tt++)
                ka[tt] = *(const bf16x8*)&Klds[p][(((tt * 2 + kd) * 4 + q) * 16 + c) * 8];
#pragma unroll
            for (int tt = 0; tt < 4; tt++)
#pragma unroll
                for (int st = 0; st < 2; st++)
                    sacc[tt][st] = mfma16(ka[tt], qf[st][kd], sacc[tt][st]);
        }

        // p = exp2(score); accumulate denominator per-lane; pack P^T -> LDS
#pragma unroll
        for (int st = 0; st < 2; st++) {
#pragma unroll
            for (int tt = 0; tt < 4; tt++) {
                float p0 = fexp2(sacc[tt][st][0]);
                float p1 = fexp2(sacc[tt][st][1]);
                float p2 = fexp2(sacc[tt][st][2]);
                float p3 = fexp2(sacc[tt][st][3]);
                lsum[st] += (p0 + p1) + (p2 + p3);
                uint2 pv; pv.x = pack2(p0, p1); pv.y = pack2(p2, p3);
                *(uint2*)&Prow[st * (16 * 72) + tt * 16 + q * 4] = pv;
            }
        }
        // (same-wave lgkmcnt ordering for P; no barrier needed)

        // O^T += VT x P^T  (A = VT rows dv, B = Plds rows s; k = t)
#pragma unroll
        for (int kt = 0; kt < 2; kt++) {
            bf16x8 va[4], pb[2];
#pragma unroll
            for (int dt = 0; dt < 4; dt++)
                va[dt] = *(const bf16x8*)&Vlds[p][(((dt * 2 + kt) * 4 + q) * 16 + c) * 8];
#pragma unroll
            for (int st = 0; st < 2; st++)
                pb[st] = *(const bf16x8*)&Prow[st * (16 * 72) + kt * 32 + q * 8];
#pragma unroll
            for (int dt = 0; dt < 4; dt++)
#pragma unroll
                for (int st = 0; st < 2; st++)
                    oacc[dt][st] = mfma16(va[dt], pb[st], oacc[dt][st]);
        }

        // (3) write staged regs into the other buffer; (4) single barrier
        *(int4*)&Klds[1 - p][tid * 8]         = kst0;
        *(int4*)&Klds[1 - p][(tid + 256) * 8] = kst1;
        *(int4*)&Vlds[1 - p][tid * 8]         = vst0;
        *(int4*)&Vlds[1 - p][(tid + 256) * 8] = vst1;
        __syncthreads();
    }

    // epilogue: attout[b][s][hd*64+dv]
    const int b = bhd >> 3, hd = bhd & 7;
#pragma unroll
    for (int st = 0; st < 2; st++) {
        float l = lsum[st];
        l += __shfl_xor(l, 16, 64);
        l += __shfl_xor(l, 32, 64);
        float rl = 1.0f / l;
        int s = s0 + wave * 32 + st * 16 + c;
#pragma unroll
        for (int dt = 0; dt < 4; dt++) {
            uint2 pv;
            pv.x = pack2(oacc[dt][st][0] * rl, oacc[dt][st][1] * rl);
            pv.y = pack2(oacc[dt][st][2] * rl, oacc[dt][st][3] * rl);
            size_t idx = ((size_t)(b * 4096 + s)) * 512 + hd * 64 + dt * 16 + q * 4;
            *(uint2*)&attout[idx] = pv;
        }
    }
}

// ---------------------------------------------------------------------------
extern "C" void kernel_launch(void* const* d_in, const int* in_sizes, int n_in,
                              void* d_out, int out_size, void* d_ws, size_t ws_size,
                              hipStream_t stream) {
    (void)in_sizes; (void)n_in; (void)out_size; (void)ws_size;
    const float* x  = (const float*)d_in[0];
    const float* Wq = (const float*)d_in[1];
    const float* bq = (const float*)d_in[2];
    const float* Wk = (const float*)d_in[3];
    const float* bk = (const float*)d_in[4];
    const float* Wv = (const float*)d_in[5];
    const float* bv = (const float*)d_in[6];
    const float* Wp = (const float*)d_in[7];
    const float* bp = (const float*)d_in[8];
    float* out = (float*)d_out;

    const size_t NTOK = (size_t)4 * 1024 * 1024;  // 2*4096*512 elements
    u16* tok = (u16*)d_ws;        // [2][4096][512] bf16; reused as attout later
    u16* Qb  = tok + NTOK;        // [16][4096][64]  (pre-scaled by log2e/8)
    u16* Kb  = Qb + NTOK;         // [16][4096][64]
    u16* Vb  = Kb + NTOK;         // [16][64][4096]
    u16* Wbf = Vb + NTOK;         // [4][512][512] bf16 (q,k,v,p)
    u16* attout = tok;            // alias: tok dead after V projection

    convert_w_kernel<<<dim3(256, 4), 256, 0, stream>>>(Wq, Wk, Wv, Wp, Wbf);
    transpose_kernel<<<dim3(64, 8, 2), 256, 0, stream>>>(x, tok);
    qkv_kernel<<<dim3(32, 4, 6), 256, 0, stream>>>(Wbf, bq, bk, bv, tok, Qb, Kb, Vb);
    attn_kernel<<<dim3(32, 16), 256, 0, stream>>>(Qb, Kb, Vb, attout);
    projp_kernel<<<dim3(32, 4, 2), 256, 0, stream>>>(Wbf + 3 * 262144, bp, attout, out);
}

// Round 8
// 224.434 us; speedup vs baseline: 1.6922x; 1.0379x over previous
//
#include <hip/hip_runtime.h>
#include <stdint.h>
#include <math.h>

typedef unsigned short u16;
typedef uint32_t u32;
typedef short bf16x8 __attribute__((ext_vector_type(8)));   // 8 bf16 = 4 VGPRs
typedef float f32x4  __attribute__((ext_vector_type(4)));

#define DEV __device__ __forceinline__

DEV u16 f2bf(float f) {
    union { float f; u32 u; } x; x.f = f;
    u32 lsb = (x.u >> 16) & 1u;
    x.u += 0x7fffu + lsb;            // RNE
    return (u16)(x.u >> 16);
}

// pack two f32 -> two bf16 (round-half-up) in 3 VALU ops
DEV u32 pack2(float a, float b) {
    union { float f; u32 u; } x, y; x.f = a; y.f = b;
    return __builtin_amdgcn_perm(y.u + 0x8000u, x.u + 0x8000u, 0x07060302u);
}

#if __has_builtin(__builtin_amdgcn_exp2f)
DEV float fexp2(float x) { return __builtin_amdgcn_exp2f(x); }
#else
DEV float fexp2(float x) { return __expf(x * 0.69314718056f); }
#endif

DEV f32x4 mfma16(bf16x8 a, bf16x8 b, f32x4 c) {
    return __builtin_amdgcn_mfma_f32_16x16x32_bf16(a, b, c, 0, 0, 0);
}

// ---------------------------------------------------------------------------
// 0) prep: fused (a) transpose+convert x[b][c][s] f32 -> tok[b][s][c] bf16
//          (b) convert 4 f32 weight matrices -> bf16 dst[j][co][ci]
//    blocks 0..1023: transpose tiles; blocks 1024..2047: weight convert.
// ---------------------------------------------------------------------------
__global__ __launch_bounds__(256) void prep_kernel(const float* __restrict__ x,
                                                   u16* __restrict__ tok,
                                                   const float* __restrict__ w0,
                                                   const float* __restrict__ w1,
                                                   const float* __restrict__ w2,
                                                   const float* __restrict__ w3,
                                                   u16* __restrict__ dst) {
    __shared__ u16 t[64][65];
    const int id = blockIdx.x, tid = threadIdx.x;
    if (id < 1024) {
        const int b = id >> 9, c0 = ((id >> 6) & 7) * 64, s0 = (id & 63) * 64;
        const float* xb = x + ((size_t)b * 512 + c0) * 4096 + s0;
        u16* tb = tok + ((size_t)b * 4096 + s0) * 512 + c0;
        {   // read: 64 rows (c) x 16 float4 cols (s)
            const int jc = tid & 15, i0 = tid >> 4;
#pragma unroll
            for (int ii = 0; ii < 4; ii++) {
                int i = i0 * 4 + ii;
                float4 v = *(const float4*)&xb[(size_t)i * 4096 + jc * 4];
                t[i][jc * 4 + 0] = f2bf(v.x);
                t[i][jc * 4 + 1] = f2bf(v.y);
                t[i][jc * 4 + 2] = f2bf(v.z);
                t[i][jc * 4 + 3] = f2bf(v.w);
            }
        }
        __syncthreads();
        {   // write: 64 rows (s) x 32 u32 cols (c pairs)
            const int j = tid & 31, i0 = tid >> 5;
#pragma unroll
            for (int ii = 0; ii < 8; ii++) {
                int srow = i0 * 8 + ii;
                u32 v = (u32)t[j * 2][srow] | ((u32)t[j * 2 + 1][srow] << 16);
                *(u32*)(&tb[(size_t)srow * 512 + j * 2]) = v;
            }
        }
    } else {
        const int id2 = id - 1024;
        const int j = id2 >> 8;
        const float* src = (j == 0) ? w0 : (j == 1) ? w1 : (j == 2) ? w2 : w3;
        int idx = ((id2 & 255) * 256 + tid) * 4;
        float4 v = *(const float4*)&src[idx];
        uint2 pv;
        pv.x = pack2(v.x, v.y);
        pv.y = pack2(v.z, v.w);
        *(uint2*)&dst[(size_t)j * 262144 + idx] = pv;
    }
}

// ---------------------------------------------------------------------------
// 2) Projection GEMM core, TRIPLE-BUFFERED, prefetch distance 2: 128x128
//    tile, BK=32, 16 K-steps, ONE barrier per step. Loads for chunk k+2 are
//    issued one full iteration before their ds_write, so the load window is
//    ~2 compute phases (covers L2/LLC latency). LDS 48 KB.
//    LDS frag order: granule g: c=g&15, q=(g>>4)&3, mt=g>>6 -> 16B of row
//    mt*16+c, k q*8. 4 waves: wave owns (wave&1) m-half x (wave>>1) n-half.
//    mode 0: out bf16 [b][hd][s][d]   mode 1: out bf16 [b*512+co][s]
//    mode 2: out f32  [b*512+co][s]
// ---------------------------------------------------------------------------
DEV void proj_core(const u16* __restrict__ W, const float* __restrict__ bias,
                   const u16* __restrict__ Bb, void* __restrict__ out,
                   int b, int mode, float scale,
                   u16 (*__restrict__ Alds)[4096], u16 (*__restrict__ Blds)[4096]) {
    const int tid = threadIdx.x;
    const int wave = tid >> 6, lane = tid & 63, q = lane >> 4, c = lane & 15;
    const int m0 = blockIdx.y * 128, n0 = blockIdx.x * 128;

    const int cs = tid & 15, qs = (tid >> 4) & 3, ms = (tid >> 6) & 3;
    const u16* Asrc0 = W  + (size_t)(m0 + ms * 16 + cs) * 512 + qs * 8;
    const u16* Asrc1 = W  + (size_t)(m0 + (ms + 4) * 16 + cs) * 512 + qs * 8;
    const u16* Bsrc0 = Bb + (size_t)(n0 + ms * 16 + cs) * 512 + qs * 8;
    const u16* Bsrc1 = Bb + (size_t)(n0 + (ms + 4) * 16 + cs) * 512 + qs * 8;

    f32x4 acc[4][4] = {};

    // prologue: chunk 0 -> LDS buf 0; chunk 1 held in registers
    int4 pa0 = *(const int4*)&Asrc0[0];
    int4 pa1 = *(const int4*)&Asrc1[0];
    int4 pb0 = *(const int4*)&Bsrc0[0];
    int4 pb1 = *(const int4*)&Bsrc1[0];
    int4 ha0 = *(const int4*)&Asrc0[32];
    int4 ha1 = *(const int4*)&Asrc1[32];
    int4 hb0 = *(const int4*)&Bsrc0[32];
    int4 hb1 = *(const int4*)&Bsrc1[32];
    *(int4*)&Alds[0][tid * 8]         = pa0;
    *(int4*)&Alds[0][(tid + 256) * 8] = pa1;
    *(int4*)&Blds[0][tid * 8]         = pb0;
    *(int4*)&Blds[0][(tid + 256) * 8] = pb1;
    __syncthreads();

    int p = 0, pw = 1;
    for (int it = 0; it < 16; it++) {
        const int kn = ((it + 2) & 15) * 32;   // chunk to prefetch (wraps; harmless)

        // (1) issue loads for chunk it+2 (consumed at iteration it+1's write)
        int4 na0 = *(const int4*)&Asrc0[kn];
        int4 na1 = *(const int4*)&Asrc1[kn];
        int4 nb0 = *(const int4*)&Bsrc0[kn];
        int4 nb1 = *(const int4*)&Bsrc1[kn];

        // (2) compute on buffer p (holds chunk it)
        bf16x8 af[4], bfr[4];
#pragma unroll
        for (int t = 0; t < 4; t++) {
            int gm = (((wave & 1) * 4 + t) * 4 + q) * 16 + c;
            af[t] = *(const bf16x8*)&Alds[p][gm * 8];
            int gn = (((wave >> 1) * 4 + t) * 4 + q) * 16 + c;
            bfr[t] = *(const bf16x8*)&Blds[p][gn * 8];
        }
#pragma unroll
        for (int mt = 0; mt < 4; mt++)
#pragma unroll
            for (int nt = 0; nt < 4; nt++)
                acc[mt][nt] = mfma16(af[mt], bfr[nt], acc[mt][nt]);

        // (3) write held chunk it+1 (loaded one iter ago) into buffer pw
        *(int4*)&Alds[pw][tid * 8]         = ha0;
        *(int4*)&Alds[pw][(tid + 256) * 8] = ha1;
        *(int4*)&Blds[pw][tid * 8]         = hb0;
        *(int4*)&Blds[pw][(tid + 256) * 8] = hb1;
        ha0 = na0; ha1 = na1; hb0 = nb0; hb1 = nb1;
        __syncthreads();
        p = pw; pw = (pw == 2) ? 0 : pw + 1;
    }

    // epilogue (validated R2): co = mbase+mt*16+q*4+reg ; s = nbase+nt*16+c
    const int mbase = m0 + (wave & 1) * 64, nbase = n0 + (wave >> 1) * 64;
#pragma unroll
    for (int mt = 0; mt < 4; mt++) {
        int co0 = mbase + mt * 16 + q * 4;
        float b0 = bias[co0 + 0], b1 = bias[co0 + 1];
        float b2 = bias[co0 + 2], b3 = bias[co0 + 3];
#pragma unroll
        for (int nt = 0; nt < 4; nt++) {
            int scol = nbase + nt * 16 + c;
            float v0 = (acc[mt][nt][0] + b0) * scale;
            float v1 = (acc[mt][nt][1] + b1) * scale;
            float v2 = (acc[mt][nt][2] + b2) * scale;
            float v3 = (acc[mt][nt][3] + b3) * scale;
            if (mode == 0) {
                uint2 pv; pv.x = pack2(v0, v1); pv.y = pack2(v2, v3);
                size_t idx = ((size_t)(b * 8 + (co0 >> 6)) * 4096 + scol) * 64 + (co0 & 63);
                *(uint2*)&((u16*)out)[idx] = pv;
            } else if (mode == 1) {
                u16* o = (u16*)out;
                o[((size_t)(b * 512 + co0 + 0)) * 4096 + scol] = f2bf(v0);
                o[((size_t)(b * 512 + co0 + 1)) * 4096 + scol] = f2bf(v1);
                o[((size_t)(b * 512 + co0 + 2)) * 4096 + scol] = f2bf(v2);
                o[((size_t)(b * 512 + co0 + 3)) * 4096 + scol] = f2bf(v3);
            } else {
                float* o = (float*)out;
                o[((size_t)(b * 512 + co0 + 0)) * 4096 + scol] = v0;
                o[((size_t)(b * 512 + co0 + 1)) * 4096 + scol] = v1;
                o[((size_t)(b * 512 + co0 + 2)) * 4096 + scol] = v2;
                o[((size_t)(b * 512 + co0 + 3)) * 4096 + scol] = v3;
            }
        }
    }
}

// fused Q/K/V projection: blockIdx.z in [0,6): j = z>>1 (0=Q,1=K,2=V), b = z&1
// Q is pre-scaled by log2(e)/8 so attention scores are in the exp2 domain.
__global__ __launch_bounds__(256) void qkv_kernel(const u16* __restrict__ Wbf,
                                                  const float* __restrict__ bq,
                                                  const float* __restrict__ bk,
                                                  const float* __restrict__ bv,
                                                  const u16* __restrict__ tok,
                                                  u16* __restrict__ Qb,
                                                  u16* __restrict__ Kb,
                                                  u16* __restrict__ Vb) {
    __shared__ u16 Alds[3][4096];    // 3 x 8KB
    __shared__ u16 Blds[3][4096];    // 3 x 8KB
    const int z = blockIdx.z, j = z >> 1, b = z & 1;
    const u16* W = Wbf + (size_t)j * 262144;
    const float* bias = (j == 0) ? bq : (j == 1) ? bk : bv;
    void* out = (j == 0) ? (void*)Qb : (j == 1) ? (void*)Kb : (void*)Vb;
    const float scale = (j == 0) ? 0.1803368801f : 1.0f;   // log2(e)/8
    const int mode = (j == 2) ? 1 : 0;
    proj_core(W, bias, tok + (size_t)b * (4096 * 512), out, b, mode, scale, Alds, Blds);
}

// final projection: blockIdx.z = batch, f32 output
__global__ __launch_bounds__(256) void projp_kernel(const u16* __restrict__ Wp,
                                                    const float* __restrict__ bp,
                                                    const u16* __restrict__ attout,
                                                    float* __restrict__ out) {
    __shared__ u16 Alds[3][4096];
    __shared__ u16 Blds[3][4096];
    const int b = blockIdx.z;
    proj_core(Wp, bp, attout + (size_t)b * (4096 * 512), out, b, 2, 1.0f, Alds, Blds);
}

// ---------------------------------------------------------------------------
// 3) Flash attention, fixed-base softmax, DOUBLE-BUFFERED K/V staging with a
//    single barrier per iteration (validated R6, unchanged). Q[bhd][s][64],
//    K[bhd][t][64], VT[bhd][64][t]. BM=128 (4 waves x 32 s-cols), BN=64
//    t-tiles. P^T shuffle is intra-wave (no barrier).
// ---------------------------------------------------------------------------
__global__ __launch_bounds__(256) void attn_kernel(const u16* __restrict__ Qm,
                                                   const u16* __restrict__ Km,
                                                   const u16* __restrict__ Vm,
                                                   u16* __restrict__ attout) {
    __shared__ u16 Klds[2][4096];     // 2 x 8KB, frag order (t4,kk,qq,r)
    __shared__ u16 Vlds[2][4096];     // 2 x 8KB, frag order (t4,kk,qq,r)
    __shared__ u16 Plds[128 * 72];    // [s_local][72] padded, 18KB (16B rows)
    const int tid = threadIdx.x, wave = tid >> 6, lane = tid & 63;
    const int q = lane >> 4, c = lane & 15;
    const int bhd = blockIdx.y, s0 = blockIdx.x * 128;
    const u16* Qb = Qm + (size_t)bhd * (4096 * 64);
    const u16* Kb = Km + (size_t)bhd * (4096 * 64);
    const u16* Vb = Vm + (size_t)bhd * (64 * 4096);

    // Q B-frags, held in registers the whole kernel (Q pre-scaled by log2e/8)
    bf16x8 qf[2][2];
#pragma unroll
    for (int st = 0; st < 2; st++)
#pragma unroll
        for (int kd = 0; kd < 2; kd++)
            qf[st][kd] = *(const bf16x8*)
                &Qb[(size_t)(s0 + wave * 32 + st * 16 + c) * 64 + kd * 32 + q * 8];

    const int rr = tid & 15, qq = (tid >> 4) & 3, kk = (tid >> 6) & 1;
    const int t40 = tid >> 7, t41 = t40 + 2;
    const u16* Ksrc0 = Kb + (size_t)(t40 * 16 + rr) * 64 + kk * 32 + qq * 8;  // + t0*64
    const u16* Ksrc1 = Kb + (size_t)(t41 * 16 + rr) * 64 + kk * 32 + qq * 8;
    const u16* Vsrc0 = Vb + (size_t)(t40 * 16 + rr) * 4096 + kk * 32 + qq * 8; // + t0
    const u16* Vsrc1 = Vb + (size_t)(t41 * 16 + rr) * 4096 + kk * 32 + qq * 8;
    u16* Prow = &Plds[(size_t)(wave * 32 + c) * 72];       // + st*16*72

    f32x4 oacc[4][2] = {};            // [dt][st]: O^T rows dv, cols s
    float lsum[2] = {0.f, 0.f};

    // prologue: stage tile 0 into buffer 0
    *(int4*)&Klds[0][tid * 8]         = *(const int4*)&Ksrc0[0];
    *(int4*)&Klds[0][(tid + 256) * 8] = *(const int4*)&Ksrc1[0];
    *(int4*)&Vlds[0][tid * 8]         = *(const int4*)&Vsrc0[0];
    *(int4*)&Vlds[0][(tid + 256) * 8] = *(const int4*)&Vsrc1[0];
    __syncthreads();

    for (int it = 0; it < 64; it++) {
        const int p = it & 1;
        const size_t t0n = (size_t)(((it + 1) & 63) * 64);  // next tile (wraps; harmless)

        // (1) issue next-tile global loads into VGPRs (land under compute)
        int4 kst0 = *(const int4*)&Ksrc0[t0n * 64];
        int4 kst1 = *(const int4*)&Ksrc1[t0n * 64];
        int4 vst0 = *(const int4*)&Vsrc0[t0n];
        int4 vst1 = *(const int4*)&Vsrc1[t0n];

        // (2) compute on buffer p
        f32x4 sacc[4][2] = {};
#pragma unroll
        for (int kd = 0; kd < 2; kd++) {
            bf16x8 ka[4];
#pragma unroll
            for (int tt = 0; tt < 4; tt++)
                ka[tt] = *(const bf16x8*)&Klds[p][(((tt * 2 + kd) * 4 + q) * 16 + c) * 8];
#pragma unroll
            for (int tt = 0; tt < 4; tt++)
#pragma unroll
                for (int st = 0; st < 2; st++)
                    sacc[tt][st] = mfma16(ka[tt], qf[st][kd], sacc[tt][st]);
        }

        // p = exp2(score); accumulate denominator per-lane; pack P^T -> LDS
#pragma unroll
        for (int st = 0; st < 2; st++) {
#pragma unroll
            for (int tt = 0; tt < 4; tt++) {
                float p0 = fexp2(sacc[tt][st][0]);
                float p1 = fexp2(sacc[tt][st][1]);
                float p2 = fexp2(sacc[tt][st][2]);
                float p3 = fexp2(sacc[tt][st][3]);
                lsum[st] += (p0 + p1) + (p2 + p3);
                uint2 pv; pv.x = pack2(p0, p1); pv.y = pack2(p2, p3);
                *(uint2*)&Prow[st * (16 * 72) + tt * 16 + q * 4] = pv;
            }
        }
        // (same-wave lgkmcnt ordering for P; no barrier needed)

        // O^T += VT x P^T  (A = VT rows dv, B = Plds rows s; k = t)
#pragma unroll
        for (int kt = 0; kt < 2; kt++) {
            bf16x8 va[4], pb[2];
#pragma unroll
            for (int dt = 0; dt < 4; dt++)
                va[dt] = *(const bf16x8*)&Vlds[p][(((dt * 2 + kt) * 4 + q) * 16 + c) * 8];
#pragma unroll
            for (int st = 0; st < 2; st++)
                pb[st] = *(const bf16x8*)&Prow[st * (16 * 72) + kt * 32 + q * 8];
#pragma unroll
            for (int dt = 0; dt < 4; dt++)
#pragma unroll
                for (int st = 0; st < 2; st++)
                    oacc[dt][st] = mfma16(va[dt], pb[st], oacc[dt][st]);
        }

        // (3) write staged regs into the other buffer; (4) single barrier
        *(int4*)&Klds[1 - p][tid * 8]         = kst0;
        *(int4*)&Klds[1 - p][(tid + 256) * 8] = kst1;
        *(int4*)&Vlds[1 - p][tid * 8]         = vst0;
        *(int4*)&Vlds[1 - p][(tid + 256) * 8] = vst1;
        __syncthreads();
    }

    // epilogue: attout[b][s][hd*64+dv]
    const int b = bhd >> 3, hd = bhd & 7;
#pragma unroll
    for (int st = 0; st < 2; st++) {
        float l = lsum[st];
        l += __shfl_xor(l, 16, 64);
        l += __shfl_xor(l, 32, 64);
        float rl = 1.0f / l;
        int s = s0 + wave * 32 + st * 16 + c;
#pragma unroll
        for (int dt = 0; dt < 4; dt++) {
            uint2 pv;
            pv.x = pack2(oacc[dt][st][0] * rl, oacc[dt][st][1] * rl);
            pv.y = pack2(oacc[dt][st][2] * rl, oacc[dt][st][3] * rl);
            size_t idx = ((size_t)(b * 4096 + s)) * 512 + hd * 64 + dt * 16 + q * 4;
            *(uint2*)&attout[idx] = pv;
        }
    }
}

// ---------------------------------------------------------------------------
extern "C" void kernel_launch(void* const* d_in, const int* in_sizes, int n_in,
                              void* d_out, int out_size, void* d_ws, size_t ws_size,
                              hipStream_t stream) {
    (void)in_sizes; (void)n_in; (void)out_size; (void)ws_size;
    const float* x  = (const float*)d_in[0];
    const float* Wq = (const float*)d_in[1];
    const float* bq = (const float*)d_in[2];
    const float* Wk = (const float*)d_in[3];
    const float* bk = (const float*)d_in[4];
    const float* Wv = (const float*)d_in[5];
    const float* bv = (const float*)d_in[6];
    const float* Wp = (const float*)d_in[7];
    const float* bp = (const float*)d_in[8];
    float* out = (float*)d_out;

    const size_t NTOK = (size_t)4 * 1024 * 1024;  // 2*4096*512 elements
    u16* tok = (u16*)d_ws;        // [2][4096][512] bf16; reused as attout later
    u16* Qb  = tok + NTOK;        // [16][4096][64]  (pre-scaled by log2e/8)
    u16* Kb  = Qb + NTOK;         // [16][4096][64]
    u16* Vb  = Kb + NTOK;         // [16][64][4096]
    u16* Wbf = Vb + NTOK;         // [4][512][512] bf16 (q,k,v,p)
    u16* attout = tok;            // alias: tok dead after V projection

    prep_kernel<<<dim3(2048), 256, 0, stream>>>(x, tok, Wq, Wk, Wv, Wp, Wbf);
    qkv_kernel<<<dim3(32, 4, 6), 256, 0, stream>>>(Wbf, bq, bk, bv, tok, Qb, Kb, Vb);
    attn_kernel<<<dim3(32, 16), 256, 0, stream>>>(Qb, Kb, Vb, attout);
    projp_kernel<<<dim3(32, 4, 2), 256, 0, stream>>>(Wbf + 3 * 262144, bp, attout, out);
}